// Round 2
// baseline (706.241 us; speedup 1.0000x reference)
//
#include <hip/hip_runtime.h>

using u16 = unsigned short;

typedef float f32x4 __attribute__((ext_vector_type(4)));
typedef __bf16 bf16x8v __attribute__((ext_vector_type(8)));
typedef bf16x8v bf16x8 __attribute__((may_alias));
typedef u16 u16x8v __attribute__((ext_vector_type(8)));
typedef u16x8v u16x8 __attribute__((may_alias));
typedef u16 u16x4v __attribute__((ext_vector_type(4)));
typedef u16x4v u16x4 __attribute__((may_alias));
typedef float f32x4v __attribute__((ext_vector_type(4)));
typedef f32x4v float4a __attribute__((may_alias));

#define GPTR(p) ((__attribute__((address_space(1))) void*)(p))
#define LPTR(p) ((__attribute__((address_space(3))) void*)(p))

__device__ __forceinline__ u16 f2bf(float f) {
  unsigned u = __builtin_bit_cast(unsigned, f);
  u += 0x7FFFu + ((u >> 16) & 1u);
  return (u16)(u >> 16);
}

__device__ __forceinline__ f32x4 mfma16(bf16x8 a, bf16x8 b, f32x4 c) {
  return __builtin_amdgcn_mfma_f32_16x16x32_bf16(a, b, c, 0, 0, 0);
}

// ---------------- fp32 -> bf16 convert ----------------
__global__ __launch_bounds__(256) void cvt_bf16(const float* __restrict__ in,
                                                u16* __restrict__ out, int n4) {
  int i = blockIdx.x * 256 + threadIdx.x;
  if (i < n4) {
    float4a v = ((const float4a*)in)[i];
    u16x4 o;
    o[0] = f2bf(v[0]); o[1] = f2bf(v[1]); o[2] = f2bf(v[2]); o[3] = f2bf(v[3]);
    ((u16x4*)out)[i] = o;
  }
}

// ---------------- LayerNorm (D=1024), fp32 in -> bf16 out ----------------
__global__ __launch_bounds__(256) void ln_k(const float* __restrict__ x,
                                            const float* __restrict__ sc,
                                            const float* __restrict__ bi,
                                            u16* __restrict__ out) {
  const int row = blockIdx.x, tid = threadIdx.x;
  float4a v = ((const float4a*)(x + (size_t)row * 1024))[tid];
  float s1 = v[0] + v[1] + v[2] + v[3];
  float s2 = v[0]*v[0] + v[1]*v[1] + v[2]*v[2] + v[3]*v[3];
#pragma unroll
  for (int off = 32; off; off >>= 1) { s1 += __shfl_xor(s1, off); s2 += __shfl_xor(s2, off); }
  __shared__ float red[8];
  if ((tid & 63) == 0) { red[tid >> 6] = s1; red[4 + (tid >> 6)] = s2; }
  __syncthreads();
  s1 = red[0] + red[1] + red[2] + red[3];
  s2 = red[4] + red[5] + red[6] + red[7];
  const float mean = s1 * (1.f / 1024.f);
  const float rstd = rsqrtf(s2 * (1.f / 1024.f) - mean * mean + 1e-6f);
  float4a s4 = ((const float4a*)sc)[tid];
  float4a b4 = ((const float4a*)bi)[tid];
  u16x4 o;
#pragma unroll
  for (int j = 0; j < 4; j++) o[j] = f2bf((v[j] - mean) * rstd * s4[j] + b4[j]);
  ((u16x4*)(out + (size_t)row * 1024))[tid] = o;
}

// ---------------- GEMM: out = epi(A[M,K] * W[N,K]^T + bias [+ C0]) ----------------
// EPI: 0 = bf16 out, bias;  1 = bf16 out, bias, relu;  2 = fp32 out, bias + C0 residual
template <int BN_T, int MW, int EPI>
__global__ __launch_bounds__(256) void gemm_bt(
    const u16* __restrict__ A, int lda,
    const u16* __restrict__ W, int ldw,
    const float* __restrict__ bias,
    const float* __restrict__ C0, int ldc0,
    void* __restrict__ outv, int ldo, int K) {
  constexpr int BM = 128, BK = 64;
  constexpr int NW = 4 / MW;
  constexpr int FM = BM / MW / 16;
  constexpr int FN = BN_T / NW / 16;
  constexpr int RA = (BM * BK * 2) / 4096;
  constexpr int RB = (BN_T * BK * 2) / 4096;
  __shared__ alignas(16) u16 As[BM * BK];
  __shared__ alignas(16) u16 Bs[BN_T * BK];
  const int tid = threadIdx.x, lane = tid & 63, wv = tid >> 6;
  const int bm = blockIdx.y * BM, bn = blockIdx.x * BN_T;
  const int wr = (wv / NW) * (BM / MW);
  const int wc = (wv % NW) * (BN_T / NW);
  const int la = lane & 15, lk = (lane >> 4) * 8;
  const int srow = wv * 8 + (lane >> 3), scol = (lane & 7) * 8;
  const u16* gA = A + (size_t)(bm + srow) * lda + scol;
  const u16* gB = W + (size_t)(bn + srow) * ldw + scol;
  u16* lA = As + (wv * 8) * BK;  // wave-uniform LDS base; HW scatters lane*16B
  u16* lB = Bs + (wv * 8) * BK;

  f32x4 acc[FM][FN] = {};

  for (int k0 = 0; k0 < K; k0 += BK) {
    __syncthreads();
#pragma unroll
    for (int r = 0; r < RA; r++)
      __builtin_amdgcn_global_load_lds(GPTR(gA + (size_t)r * 32 * lda + k0),
                                       LPTR(lA + r * 32 * BK), 16, 0, 0);
#pragma unroll
    for (int r = 0; r < RB; r++)
      __builtin_amdgcn_global_load_lds(GPTR(gB + (size_t)r * 32 * ldw + k0),
                                       LPTR(lB + r * 32 * BK), 16, 0, 0);
    __syncthreads();
#pragma unroll
    for (int kk = 0; kk < BK; kk += 32) {
      bf16x8 af[FM], bfr[FN];
#pragma unroll
      for (int m = 0; m < FM; m++) af[m] = *(const bf16x8*)&As[(wr + m * 16 + la) * BK + kk + lk];
#pragma unroll
      for (int n = 0; n < FN; n++) bfr[n] = *(const bf16x8*)&Bs[(wc + n * 16 + la) * BK + kk + lk];
#pragma unroll
      for (int m = 0; m < FM; m++)
#pragma unroll
        for (int n = 0; n < FN; n++)
          acc[m][n] = mfma16(af[m], bfr[n], acc[m][n]);
    }
  }
  float bv[FN];
#pragma unroll
  for (int n = 0; n < FN; n++) bv[n] = bias[bn + wc + n * 16 + la];
#pragma unroll
  for (int m = 0; m < FM; m++) {
#pragma unroll
    for (int j = 0; j < 4; j++) {
      const int row = bm + wr + m * 16 + (lane >> 4) * 4 + j;
#pragma unroll
      for (int n = 0; n < FN; n++) {
        const int col = bn + wc + n * 16 + la;
        float v = acc[m][n][j] + bv[n];
        if constexpr (EPI == 1) v = fmaxf(v, 0.f);
        if constexpr (EPI == 2) {
          ((float*)outv)[(size_t)row * ldo + col] = v + C0[(size_t)row * ldc0 + col];
        } else {
          ((u16*)outv)[(size_t)row * ldo + col] = f2bf(v);
        }
      }
    }
  }
}

// ---------------- fused attention (flash-style), hd=64, H=16 ----------------
// grid: (Tq/64, B*H); block 256 (4 waves, 16 q-rows each). KV tile = 128.
template <bool CAUSAL>
__global__ __launch_bounds__(256) void attn_k(
    const u16* __restrict__ Qb, int ldq,
    const u16* __restrict__ Kb, int ldk,
    const u16* __restrict__ Vb, int ldv,
    const float* __restrict__ rel,   // [256,16]
    u16* __restrict__ Ob, int ldo,
    int Tq, int Tk) {
  __shared__ alignas(16) u16 Ks[128][72];     // +8 pad: 2-way banks on frag reads
  __shared__ alignas(16) u16 Vt[64][136];     // V transposed [d][kv], +8 pad
  __shared__ alignas(16) u16 Ps[4][16][136];  // per-wave P tile [q][kv], +8 pad
  __shared__ float biasl[256];
  const int tid = threadIdx.x, lane = tid & 63, w = tid >> 6;
  const int b = blockIdx.y >> 4, h = blockIdx.y & 15;
  const int q0 = blockIdx.x * 64;
  const int la = lane & 15, lg = lane >> 4;

  biasl[tid] = rel[tid * 16 + h];

  const int qr0 = q0 + w * 16;
  const u16* qp = Qb + (size_t)(b * Tq + qr0 + la) * ldq + h * 64 + lg * 8;
  const bf16x8 qf0 = *(const bf16x8*)qp;
  const bf16x8 qf1 = *(const bf16x8*)(qp + 32);

  float m[4], sm[4];
  f32x4 acc[4] = {};
#pragma unroll
  for (int j = 0; j < 4; j++) { m[j] = -1e30f; sm[j] = 0.f; }

  const int kv_end = CAUSAL ? (q0 + 64) : Tk;
  const int srow = tid >> 3, scol = (tid & 7) * 8;
  for (int kv0 = 0; kv0 < kv_end; kv0 += 128) {
    __syncthreads();
#pragma unroll
    for (int r = 0; r < 4; r++) {
      const int row = r * 32 + srow;
      const size_t gr = (size_t)(b * Tk + kv0 + row);
      *(u16x8*)&Ks[row][scol] = *(const u16x8*)&Kb[gr * ldk + h * 64 + scol];
      u16x8 vv = *(const u16x8*)&Vb[gr * ldv + h * 64 + scol];
#pragma unroll
      for (int j = 0; j < 8; j++) Vt[scol + j][row] = vv[j];
    }
    __syncthreads();

    f32x4 s[8];
#pragma unroll
    for (int kvt = 0; kvt < 8; kvt++) {
      const bf16x8 kf0 = *(const bf16x8*)&Ks[kvt * 16 + la][lg * 8];
      const bf16x8 kf1 = *(const bf16x8*)&Ks[kvt * 16 + la][32 + lg * 8];
      f32x4 t = {};
      t = mfma16(qf0, kf0, t);
      t = mfma16(qf1, kf1, t);
      const int kc = kv0 + kvt * 16 + la;
#pragma unroll
      for (int j = 0; j < 4; j++) {
        const int qr = qr0 + lg * 4 + j;
        const int rp = kc - qr;
        const int bucket = rp < 0 ? (rp > -127 ? -rp : 127) : (rp < 127 ? rp : 127) + 128;
        float sv = t[j] * 0.125f + biasl[bucket];
        if (CAUSAL && kc > qr) sv = -1e30f;
        s[kvt][j] = sv;
      }
    }
    float alpha[4];
#pragma unroll
    for (int j = 0; j < 4; j++) {
      float tm = s[0][j];
#pragma unroll
      for (int kvt = 1; kvt < 8; kvt++) tm = fmaxf(tm, s[kvt][j]);
#pragma unroll
      for (int off = 1; off < 16; off <<= 1) tm = fmaxf(tm, __shfl_xor(tm, off));
      const float mn = fmaxf(m[j], tm);
      alpha[j] = __expf(m[j] - mn);
      m[j] = mn;
      float r = 0.f;
#pragma unroll
      for (int kvt = 0; kvt < 8; kvt++) {
        const float p = __expf(s[kvt][j] - mn);
        s[kvt][j] = p;
        r += p;
      }
#pragma unroll
      for (int off = 1; off < 16; off <<= 1) r += __shfl_xor(r, off);
      sm[j] = sm[j] * alpha[j] + r;
    }
#pragma unroll
    for (int kvt = 0; kvt < 8; kvt++)
#pragma unroll
      for (int j = 0; j < 4; j++)
        Ps[w][lg * 4 + j][kvt * 16 + la] = f2bf(s[kvt][j]);
#pragma unroll
    for (int n = 0; n < 4; n++)
#pragma unroll
      for (int j = 0; j < 4; j++)
        acc[n][j] *= alpha[j];
#pragma unroll
    for (int kq = 0; kq < 4; kq++) {
      const bf16x8 pf = *(const bf16x8*)&Ps[w][la][kq * 32 + lg * 8];
#pragma unroll
      for (int n = 0; n < 4; n++) {
        const bf16x8 vf = *(const bf16x8*)&Vt[n * 16 + la][kq * 32 + lg * 8];
        acc[n] = mfma16(pf, vf, acc[n]);
      }
    }
  }
#pragma unroll
  for (int n = 0; n < 4; n++)
#pragma unroll
    for (int j = 0; j < 4; j++) {
      const int qr = qr0 + lg * 4 + j;
      Ob[(size_t)(b * Tq + qr) * ldo + h * 64 + n * 16 + la] = f2bf(acc[n][j] / sm[j]);
    }
}

extern "C" void kernel_launch(void* const* d_in, const int* in_sizes, int n_in,
                              void* d_out, int out_size, void* d_ws, size_t ws_size,
                              hipStream_t stream) {
  (void)in_sizes; (void)n_in; (void)out_size; (void)ws_size;
  const float* src       = (const float*)d_in[0];
  const float* tgt       = (const float*)d_in[1];
  const float* enc_in_w  = (const float*)d_in[2];
  const float* enc_in_b  = (const float*)d_in[3];
  const float* enc_out_w = (const float*)d_in[4];
  const float* enc_out_b = (const float*)d_in[5];
  const float* enc_ff1_w = (const float*)d_in[6];
  const float* enc_ff1_b = (const float*)d_in[7];
  const float* enc_ff2_w = (const float*)d_in[8];
  const float* enc_ff2_b = (const float*)d_in[9];
  const float* enc_n1_s  = (const float*)d_in[10];
  const float* enc_n1_b  = (const float*)d_in[11];
  const float* enc_n2_s  = (const float*)d_in[12];
  const float* enc_n2_b  = (const float*)d_in[13];
  const float* enc_rel   = (const float*)d_in[14];
  const float* dsa_in_w  = (const float*)d_in[15];
  const float* dsa_in_b  = (const float*)d_in[16];
  const float* dsa_out_w = (const float*)d_in[17];
  const float* dsa_out_b = (const float*)d_in[18];
  const float* dca_in_w  = (const float*)d_in[19];
  const float* dca_in_b  = (const float*)d_in[20];
  const float* dca_out_w = (const float*)d_in[21];
  const float* dca_out_b = (const float*)d_in[22];
  const float* dff1_w    = (const float*)d_in[23];
  const float* dff1_b    = (const float*)d_in[24];
  const float* dff2_w    = (const float*)d_in[25];
  const float* dff2_b    = (const float*)d_in[26];
  const float* dn1_s     = (const float*)d_in[27];
  const float* dn1_b     = (const float*)d_in[28];
  const float* dn2_s     = (const float*)d_in[29];
  const float* dn2_b     = (const float*)d_in[30];
  const float* dn3_s     = (const float*)d_in[31];
  const float* dn3_b     = (const float*)d_in[32];
  const float* drel_s    = (const float*)d_in[33];
  const float* drel_c    = (const float*)d_in[34];
  float* fo = (float*)d_out;

  // workspace layout (120 MB total)
  char* w8 = (char*)d_ws;
  float* x_ws  = (float*)(w8 + 0);          // 16,777,216 B  encoder residual
  u16* ln_buf  = (u16*)(w8 + 16777216);     //  8,388,608 B
  u16* qkv     = (u16*)(w8 + 25165824);     // 25,165,824 B
  u16* attn_o  = (u16*)(w8 + 50331648);     //  8,388,608 B
  u16* ffh     = qkv;                       // 33,554,432 B  (aliases qkv+attn_o)
  u16* memb    = (u16*)(w8 + 58720256);     //  8,388,608 B  bf16 encoder memory
  u16* wb      = (u16*)(w8 + 67108864);     // 58,720,256 B  bf16 weights

  u16* w_enc_in  = wb;
  u16* w_enc_out = wb + 3145728;
  u16* w_enc_f1  = wb + 4194304;
  u16* w_enc_f2  = wb + 8388608;
  u16* w_dsa_in  = wb + 12582912;
  u16* w_dsa_out = wb + 15728640;
  u16* w_dca_in  = wb + 16777216;
  u16* w_dca_out = wb + 19922944;
  u16* w_dff1    = wb + 20971520;
  u16* w_dff2    = wb + 25165824;

#define CVT(sp, dp, n) cvt_bf16<<<dim3((n) / 1024), 256, 0, stream>>>(sp, dp, (n) / 4)
  CVT(enc_in_w,  w_enc_in,  3145728);
  CVT(enc_out_w, w_enc_out, 1048576);
  CVT(enc_ff1_w, w_enc_f1,  4194304);
  CVT(enc_ff2_w, w_enc_f2,  4194304);
  CVT(dsa_in_w,  w_dsa_in,  3145728);
  CVT(dsa_out_w, w_dsa_out, 1048576);
  CVT(dca_in_w,  w_dca_in,  3145728);
  CVT(dca_out_w, w_dca_out, 1048576);
  CVT(dff1_w,    w_dff1,    4194304);
  CVT(dff2_w,    w_dff2,    4194304);
#undef CVT

  // ---------------- encoder layer ----------------
  ln_k<<<dim3(4096), 256, 0, stream>>>(src, enc_n1_s, enc_n1_b, ln_buf);
  gemm_bt<128,2,0><<<dim3(24, 32), 256, 0, stream>>>(ln_buf, 1024, w_enc_in, 1024, enc_in_b, nullptr, 0, qkv, 3072, 1024);
  attn_k<false><<<dim3(8, 128), 256, 0, stream>>>(qkv, 3072, qkv + 1024, 3072, qkv + 2048, 3072, enc_rel, attn_o, 1024, 512, 512);
  gemm_bt<64,4,2><<<dim3(16, 32), 256, 0, stream>>>(attn_o, 1024, w_enc_out, 1024, enc_out_b, src, 1024, x_ws, 1024, 1024);
  ln_k<<<dim3(4096), 256, 0, stream>>>(x_ws, enc_n2_s, enc_n2_b, ln_buf);
  gemm_bt<128,2,1><<<dim3(32, 32), 256, 0, stream>>>(ln_buf, 1024, w_enc_f1, 1024, enc_ff1_b, nullptr, 0, ffh, 4096, 1024);
  gemm_bt<64,4,2><<<dim3(16, 32), 256, 0, stream>>>(ffh, 4096, w_enc_f2, 4096, enc_ff2_b, x_ws, 1024, x_ws, 1024, 4096);
  cvt_bf16<<<dim3(4096), 256, 0, stream>>>(x_ws, memb, 1048576);

  // ---------------- decoder layer ----------------
  ln_k<<<dim3(4096), 256, 0, stream>>>(tgt, dn1_s, dn1_b, ln_buf);
  gemm_bt<128,2,0><<<dim3(24, 32), 256, 0, stream>>>(ln_buf, 1024, w_dsa_in, 1024, dsa_in_b, nullptr, 0, qkv, 3072, 1024);
  attn_k<true><<<dim3(8, 128), 256, 0, stream>>>(qkv, 3072, qkv + 1024, 3072, qkv + 2048, 3072, drel_s, attn_o, 1024, 512, 512);
  gemm_bt<64,4,2><<<dim3(16, 32), 256, 0, stream>>>(attn_o, 1024, w_dsa_out, 1024, dsa_out_b, tgt, 1024, fo, 1024, 1024);

  ln_k<<<dim3(4096), 256, 0, stream>>>(fo, dn2_s, dn2_b, ln_buf);
  gemm_bt<64,4,0><<<dim3(16, 32), 256, 0, stream>>>(ln_buf, 1024, w_dca_in, 1024, dca_in_b, nullptr, 0, qkv, 3072, 1024);
  gemm_bt<128,2,0><<<dim3(16, 32), 256, 0, stream>>>(memb, 1024, w_dca_in + 1048576, 1024, dca_in_b + 1024, nullptr, 0, qkv + 1024, 3072, 1024);
  attn_k<false><<<dim3(8, 128), 256, 0, stream>>>(qkv, 3072, qkv + 1024, 3072, qkv + 2048, 3072, drel_c, attn_o, 1024, 512, 512);
  gemm_bt<64,4,2><<<dim3(16, 32), 256, 0, stream>>>(attn_o, 1024, w_dca_out, 1024, dca_out_b, fo, 1024, fo, 1024, 1024);

  ln_k<<<dim3(4096), 256, 0, stream>>>(fo, dn3_s, dn3_b, ln_buf);
  gemm_bt<128,2,1><<<dim3(32, 32), 256, 0, stream>>>(ln_buf, 1024, w_dff1, 1024, dff1_b, nullptr, 0, ffh, 4096, 1024);
  gemm_bt<64,4,2><<<dim3(16, 32), 256, 0, stream>>>(ffh, 4096, w_dff2, 4096, dff2_b, fo, 1024, fo, 1024, 4096);
}

// Round 3
// 704.763 us; speedup vs baseline: 1.0021x; 1.0021x over previous
//
#include <hip/hip_runtime.h>

using u16 = unsigned short;

typedef float f32x4 __attribute__((ext_vector_type(4)));
typedef __bf16 bf16x8v __attribute__((ext_vector_type(8)));
typedef bf16x8v bf16x8 __attribute__((may_alias));
typedef u16 u16x8v __attribute__((ext_vector_type(8)));
typedef u16x8v u16x8 __attribute__((may_alias));
typedef u16 u16x4v __attribute__((ext_vector_type(4)));
typedef u16x4v u16x4 __attribute__((may_alias));
typedef float f32x4v __attribute__((ext_vector_type(4)));
typedef f32x4v float4a __attribute__((may_alias));

#define GPTR(p) ((__attribute__((address_space(1))) void*)(p))
#define LPTR(p) ((__attribute__((address_space(3))) void*)(p))

__device__ __forceinline__ u16 f2bf(float f) {
  unsigned u = __builtin_bit_cast(unsigned, f);
  u += 0x7FFFu + ((u >> 16) & 1u);
  return (u16)(u >> 16);
}

__device__ __forceinline__ f32x4 mfma16(bf16x8 a, bf16x8 b, f32x4 c) {
  return __builtin_amdgcn_mfma_f32_16x16x32_bf16(a, b, c, 0, 0, 0);
}

// ---------------- fp32 -> bf16 convert ----------------
__global__ __launch_bounds__(256) void cvt_bf16(const float* __restrict__ in,
                                                u16* __restrict__ out, int n4) {
  int i = blockIdx.x * 256 + threadIdx.x;
  if (i < n4) {
    float4a v = ((const float4a*)in)[i];
    u16x4 o;
    o[0] = f2bf(v[0]); o[1] = f2bf(v[1]); o[2] = f2bf(v[2]); o[3] = f2bf(v[3]);
    ((u16x4*)out)[i] = o;
  }
}

// ---------------- LayerNorm (D=1024), fp32 in -> bf16 out ----------------
__global__ __launch_bounds__(256) void ln_k(const float* __restrict__ x,
                                            const float* __restrict__ sc,
                                            const float* __restrict__ bi,
                                            u16* __restrict__ out) {
  const int row = blockIdx.x, tid = threadIdx.x;
  float4a v = ((const float4a*)(x + (size_t)row * 1024))[tid];
  float s1 = v[0] + v[1] + v[2] + v[3];
  float s2 = v[0]*v[0] + v[1]*v[1] + v[2]*v[2] + v[3]*v[3];
#pragma unroll
  for (int off = 32; off; off >>= 1) { s1 += __shfl_xor(s1, off); s2 += __shfl_xor(s2, off); }
  __shared__ float red[8];
  if ((tid & 63) == 0) { red[tid >> 6] = s1; red[4 + (tid >> 6)] = s2; }
  __syncthreads();
  s1 = red[0] + red[1] + red[2] + red[3];
  s2 = red[4] + red[5] + red[6] + red[7];
  const float mean = s1 * (1.f / 1024.f);
  const float rstd = rsqrtf(s2 * (1.f / 1024.f) - mean * mean + 1e-6f);
  float4a s4 = ((const float4a*)sc)[tid];
  float4a b4 = ((const float4a*)bi)[tid];
  u16x4 o;
#pragma unroll
  for (int j = 0; j < 4; j++) o[j] = f2bf((v[j] - mean) * rstd * s4[j] + b4[j]);
  ((u16x4*)(out + (size_t)row * 1024))[tid] = o;
}

// ---------------- GEMM: out = epi(A[M,K] * W[N,K]^T + bias [+ C0]) ----------------
// EPI: 0 = bf16 out, bias;  1 = bf16 out, bias, relu;  2 = fp32 out, bias + C0 residual
template <int BN_T, int MW, int EPI>
__global__ __launch_bounds__(256) void gemm_bt(
    const u16* __restrict__ A, int lda,
    const u16* __restrict__ W, int ldw,
    const float* __restrict__ bias,
    const float* __restrict__ C0, int ldc0,
    void* __restrict__ outv, int ldo, int K) {
  constexpr int BM = 128, BK = 64;
  constexpr int NW = 4 / MW;
  constexpr int FM = BM / MW / 16;
  constexpr int FN = BN_T / NW / 16;
  constexpr int RA = (BM * BK * 2) / 4096;
  constexpr int RB = (BN_T * BK * 2) / 4096;
  __shared__ alignas(16) u16 As[BM * BK];
  __shared__ alignas(16) u16 Bs[BN_T * BK];
  const int tid = threadIdx.x, lane = tid & 63, wv = tid >> 6;
  const int bm = blockIdx.y * BM, bn = blockIdx.x * BN_T;
  const int wr = (wv / NW) * (BM / MW);
  const int wc = (wv % NW) * (BN_T / NW);
  const int la = lane & 15, lk = (lane >> 4) * 8;
  const int srow = wv * 8 + (lane >> 3), scol = (lane & 7) * 8;
  const u16* gA = A + (size_t)(bm + srow) * lda + scol;
  const u16* gB = W + (size_t)(bn + srow) * ldw + scol;
  u16* lA = As + (wv * 8) * BK;  // wave-uniform LDS base; HW scatters lane*16B
  u16* lB = Bs + (wv * 8) * BK;

  f32x4 acc[FM][FN] = {};

  for (int k0 = 0; k0 < K; k0 += BK) {
    __syncthreads();
#pragma unroll
    for (int r = 0; r < RA; r++)
      __builtin_amdgcn_global_load_lds(GPTR(gA + (size_t)r * 32 * lda + k0),
                                       LPTR(lA + r * 32 * BK), 16, 0, 0);
#pragma unroll
    for (int r = 0; r < RB; r++)
      __builtin_amdgcn_global_load_lds(GPTR(gB + (size_t)r * 32 * ldw + k0),
                                       LPTR(lB + r * 32 * BK), 16, 0, 0);
    __syncthreads();
#pragma unroll
    for (int kk = 0; kk < BK; kk += 32) {
      bf16x8 af[FM], bfr[FN];
#pragma unroll
      for (int m = 0; m < FM; m++) af[m] = *(const bf16x8*)&As[(wr + m * 16 + la) * BK + kk + lk];
#pragma unroll
      for (int n = 0; n < FN; n++) bfr[n] = *(const bf16x8*)&Bs[(wc + n * 16 + la) * BK + kk + lk];
#pragma unroll
      for (int m = 0; m < FM; m++)
#pragma unroll
        for (int n = 0; n < FN; n++)
          acc[m][n] = mfma16(af[m], bfr[n], acc[m][n]);
    }
  }
  float bv[FN];
#pragma unroll
  for (int n = 0; n < FN; n++) bv[n] = bias[bn + wc + n * 16 + la];
#pragma unroll
  for (int m = 0; m < FM; m++) {
#pragma unroll
    for (int j = 0; j < 4; j++) {
      const int row = bm + wr + m * 16 + (lane >> 4) * 4 + j;
#pragma unroll
      for (int n = 0; n < FN; n++) {
        const int col = bn + wc + n * 16 + la;
        float v = acc[m][n][j] + bv[n];
        if constexpr (EPI == 1) v = fmaxf(v, 0.f);
        if constexpr (EPI == 2) {
          ((float*)outv)[(size_t)row * ldo + col] = v + C0[(size_t)row * ldc0 + col];
        } else {
          ((u16*)outv)[(size_t)row * ldo + col] = f2bf(v);
        }
      }
    }
  }
}

// ---------------- fused attention (flash-style), hd=64, H=16 ----------------
// grid: (Tq/64, B*H); block 256 (4 waves, 16 q-rows each). KV tile = 128.
template <bool CAUSAL>
__global__ __launch_bounds__(256) void attn_k(
    const u16* __restrict__ Qb, int ldq,
    const u16* __restrict__ Kb, int ldk,
    const u16* __restrict__ Vb, int ldv,
    const float* __restrict__ rel,   // [256,16]
    u16* __restrict__ Ob, int ldo,
    int Tq, int Tk) {
  __shared__ alignas(16) u16 Ks[128][72];     // +8 pad: 2-way banks on frag reads
  __shared__ alignas(16) u16 Vt[64][136];     // V transposed [d][kv], +8 pad
  __shared__ alignas(16) u16 Ps[4][16][136];  // per-wave P tile [q][kv], +8 pad
  __shared__ float biasl[256];
  const int tid = threadIdx.x, lane = tid & 63, w = tid >> 6;
  const int b = blockIdx.y >> 4, h = blockIdx.y & 15;
  const int q0 = blockIdx.x * 64;
  const int la = lane & 15, lg = lane >> 4;

  biasl[tid] = rel[tid * 16 + h];

  const int qr0 = q0 + w * 16;
  const u16* qp = Qb + (size_t)(b * Tq + qr0 + la) * ldq + h * 64 + lg * 8;
  const bf16x8 qf0 = *(const bf16x8*)qp;
  const bf16x8 qf1 = *(const bf16x8*)(qp + 32);

  float m[4], sm[4];
  f32x4 acc[4] = {};
#pragma unroll
  for (int j = 0; j < 4; j++) { m[j] = -1e30f; sm[j] = 0.f; }

  const int kv_end = CAUSAL ? (q0 + 64) : Tk;
  const int srow = tid >> 3, scol = (tid & 7) * 8;
  for (int kv0 = 0; kv0 < kv_end; kv0 += 128) {
    __syncthreads();
#pragma unroll
    for (int r = 0; r < 4; r++) {
      const int row = r * 32 + srow;
      const size_t gr = (size_t)(b * Tk + kv0 + row);
      *(u16x8*)&Ks[row][scol] = *(const u16x8*)&Kb[gr * ldk + h * 64 + scol];
      u16x8 vv = *(const u16x8*)&Vb[gr * ldv + h * 64 + scol];
#pragma unroll
      for (int j = 0; j < 8; j++) Vt[scol + j][row] = vv[j];
    }
    __syncthreads();

    f32x4 s[8];
#pragma unroll
    for (int kvt = 0; kvt < 8; kvt++) {
      const bf16x8 kf0 = *(const bf16x8*)&Ks[kvt * 16 + la][lg * 8];
      const bf16x8 kf1 = *(const bf16x8*)&Ks[kvt * 16 + la][32 + lg * 8];
      f32x4 t = {};
      t = mfma16(qf0, kf0, t);
      t = mfma16(qf1, kf1, t);
      const int kc = kv0 + kvt * 16 + la;
#pragma unroll
      for (int j = 0; j < 4; j++) {
        const int qr = qr0 + lg * 4 + j;
        const int rp = kc - qr;
        const int bucket = rp < 0 ? (rp > -127 ? -rp : 127) : (rp < 127 ? rp : 127) + 128;
        float sv = t[j] * 0.125f + biasl[bucket];
        if (CAUSAL && kc > qr) sv = -1e30f;
        s[kvt][j] = sv;
      }
    }
    float alpha[4];
#pragma unroll
    for (int j = 0; j < 4; j++) {
      float tm = s[0][j];
#pragma unroll
      for (int kvt = 1; kvt < 8; kvt++) tm = fmaxf(tm, s[kvt][j]);
#pragma unroll
      for (int off = 1; off < 16; off <<= 1) tm = fmaxf(tm, __shfl_xor(tm, off));
      const float mn = fmaxf(m[j], tm);
      alpha[j] = __expf(m[j] - mn);
      m[j] = mn;
      float r = 0.f;
#pragma unroll
      for (int kvt = 0; kvt < 8; kvt++) {
        const float p = __expf(s[kvt][j] - mn);
        s[kvt][j] = p;
        r += p;
      }
#pragma unroll
      for (int off = 1; off < 16; off <<= 1) r += __shfl_xor(r, off);
      sm[j] = sm[j] * alpha[j] + r;
    }
#pragma unroll
    for (int kvt = 0; kvt < 8; kvt++)
#pragma unroll
      for (int j = 0; j < 4; j++)
        Ps[w][lg * 4 + j][kvt * 16 + la] = f2bf(s[kvt][j]);
#pragma unroll
    for (int n = 0; n < 4; n++)
#pragma unroll
      for (int j = 0; j < 4; j++)
        acc[n][j] *= alpha[j];
#pragma unroll
    for (int kq = 0; kq < 4; kq++) {
      const bf16x8 pf = *(const bf16x8*)&Ps[w][la][kq * 32 + lg * 8];
#pragma unroll
      for (int n = 0; n < 4; n++) {
        const bf16x8 vf = *(const bf16x8*)&Vt[n * 16 + la][kq * 32 + lg * 8];
        acc[n] = mfma16(pf, vf, acc[n]);
      }
    }
  }
#pragma unroll
  for (int n = 0; n < 4; n++)
#pragma unroll
    for (int j = 0; j < 4; j++) {
      const int qr = qr0 + lg * 4 + j;
      Ob[(size_t)(b * Tq + qr) * ldo + h * 64 + n * 16 + la] = f2bf(acc[n][j] / sm[j]);
    }
}

extern "C" void kernel_launch(void* const* d_in, const int* in_sizes, int n_in,
                              void* d_out, int out_size, void* d_ws, size_t ws_size,
                              hipStream_t stream) {
  (void)in_sizes; (void)n_in; (void)out_size; (void)ws_size;
  const float* src       = (const float*)d_in[0];
  const float* tgt       = (const float*)d_in[1];
  const float* enc_in_w  = (const float*)d_in[2];
  const float* enc_in_b  = (const float*)d_in[3];
  const float* enc_out_w = (const float*)d_in[4];
  const float* enc_out_b = (const float*)d_in[5];
  const float* enc_ff1_w = (const float*)d_in[6];
  const float* enc_ff1_b = (const float*)d_in[7];
  const float* enc_ff2_w = (const float*)d_in[8];
  const float* enc_ff2_b = (const float*)d_in[9];
  const float* enc_n1_s  = (const float*)d_in[10];
  const float* enc_n1_b  = (const float*)d_in[11];
  const float* enc_n2_s  = (const float*)d_in[12];
  const float* enc_n2_b  = (const float*)d_in[13];
  const float* enc_rel   = (const float*)d_in[14];
  const float* dsa_in_w  = (const float*)d_in[15];
  const float* dsa_in_b  = (const float*)d_in[16];
  const float* dsa_out_w = (const float*)d_in[17];
  const float* dsa_out_b = (const float*)d_in[18];
  const float* dca_in_w  = (const float*)d_in[19];
  const float* dca_in_b  = (const float*)d_in[20];
  const float* dca_out_w = (const float*)d_in[21];
  const float* dca_out_b = (const float*)d_in[22];
  const float* dff1_w    = (const float*)d_in[23];
  const float* dff1_b    = (const float*)d_in[24];
  const float* dff2_w    = (const float*)d_in[25];
  const float* dff2_b    = (const float*)d_in[26];
  const float* dn1_s     = (const float*)d_in[27];
  const float* dn1_b     = (const float*)d_in[28];
  const float* dn2_s     = (const float*)d_in[29];
  const float* dn2_b     = (const float*)d_in[30];
  const float* dn3_s     = (const float*)d_in[31];
  const float* dn3_b     = (const float*)d_in[32];
  const float* drel_s    = (const float*)d_in[33];
  const float* drel_c    = (const float*)d_in[34];
  float* fo = (float*)d_out;

  // workspace layout (120 MB total)
  char* w8 = (char*)d_ws;
  float* x_ws  = (float*)(w8 + 0);          // 16,777,216 B  encoder residual
  u16* ln_buf  = (u16*)(w8 + 16777216);     //  8,388,608 B
  u16* qkv     = (u16*)(w8 + 25165824);     // 25,165,824 B
  u16* attn_o  = (u16*)(w8 + 50331648);     //  8,388,608 B
  u16* ffh     = qkv;                       // 33,554,432 B  (aliases qkv+attn_o)
  u16* memb    = (u16*)(w8 + 58720256);     //  8,388,608 B  bf16 encoder memory
  u16* wb      = (u16*)(w8 + 67108864);     // 58,720,256 B  bf16 weights

  u16* w_enc_in  = wb;
  u16* w_enc_out = wb + 3145728;
  u16* w_enc_f1  = wb + 4194304;
  u16* w_enc_f2  = wb + 8388608;
  u16* w_dsa_in  = wb + 12582912;
  u16* w_dsa_out = wb + 15728640;
  u16* w_dca_in  = wb + 16777216;
  u16* w_dca_out = wb + 19922944;
  u16* w_dff1    = wb + 20971520;
  u16* w_dff2    = wb + 25165824;

#define CVT(sp, dp, n) cvt_bf16<<<dim3((n) / 1024), 256, 0, stream>>>(sp, dp, (n) / 4)
  CVT(enc_in_w,  w_enc_in,  3145728);
  CVT(enc_out_w, w_enc_out, 1048576);
  CVT(enc_ff1_w, w_enc_f1,  4194304);
  CVT(enc_ff2_w, w_enc_f2,  4194304);
  CVT(dsa_in_w,  w_dsa_in,  3145728);
  CVT(dsa_out_w, w_dsa_out, 1048576);
  CVT(dca_in_w,  w_dca_in,  3145728);
  CVT(dca_out_w, w_dca_out, 1048576);
  CVT(dff1_w,    w_dff1,    4194304);
  CVT(dff2_w,    w_dff2,    4194304);
#undef CVT

  // ---------------- encoder layer ----------------
  ln_k<<<dim3(4096), 256, 0, stream>>>(src, enc_n1_s, enc_n1_b, ln_buf);
  gemm_bt<128,2,0><<<dim3(24, 32), 256, 0, stream>>>(ln_buf, 1024, w_enc_in, 1024, enc_in_b, nullptr, 0, qkv, 3072, 1024);
  attn_k<false><<<dim3(8, 128), 256, 0, stream>>>(qkv, 3072, qkv + 1024, 3072, qkv + 2048, 3072, enc_rel, attn_o, 1024, 512, 512);
  gemm_bt<64,4,2><<<dim3(16, 32), 256, 0, stream>>>(attn_o, 1024, w_enc_out, 1024, enc_out_b, src, 1024, x_ws, 1024, 1024);
  ln_k<<<dim3(4096), 256, 0, stream>>>(x_ws, enc_n2_s, enc_n2_b, ln_buf);
  gemm_bt<128,2,1><<<dim3(32, 32), 256, 0, stream>>>(ln_buf, 1024, w_enc_f1, 1024, enc_ff1_b, nullptr, 0, ffh, 4096, 1024);
  gemm_bt<64,4,2><<<dim3(16, 32), 256, 0, stream>>>(ffh, 4096, w_enc_f2, 4096, enc_ff2_b, x_ws, 1024, x_ws, 1024, 4096);
  cvt_bf16<<<dim3(4096), 256, 0, stream>>>(x_ws, memb, 1048576);

  // ---------------- decoder layer ----------------
  ln_k<<<dim3(4096), 256, 0, stream>>>(tgt, dn1_s, dn1_b, ln_buf);
  gemm_bt<128,2,0><<<dim3(24, 32), 256, 0, stream>>>(ln_buf, 1024, w_dsa_in, 1024, dsa_in_b, nullptr, 0, qkv, 3072, 1024);
  attn_k<true><<<dim3(8, 128), 256, 0, stream>>>(qkv, 3072, qkv + 1024, 3072, qkv + 2048, 3072, drel_s, attn_o, 1024, 512, 512);
  gemm_bt<64,4,2><<<dim3(16, 32), 256, 0, stream>>>(attn_o, 1024, w_dsa_out, 1024, dsa_out_b, tgt, 1024, fo, 1024, 1024);

  ln_k<<<dim3(4096), 256, 0, stream>>>(fo, dn2_s, dn2_b, ln_buf);
  gemm_bt<64,4,0><<<dim3(16, 32), 256, 0, stream>>>(ln_buf, 1024, w_dca_in, 1024, dca_in_b, nullptr, 0, qkv, 3072, 1024);
  gemm_bt<128,2,0><<<dim3(16, 32), 256, 0, stream>>>(memb, 1024, w_dca_in + 1048576, 1024, dca_in_b + 1024, nullptr, 0, qkv + 1024, 3072, 1024);
  attn_k<false><<<dim3(8, 128), 256, 0, stream>>>(qkv, 3072, qkv + 1024, 3072, qkv + 2048, 3072, drel_c, attn_o, 1024, 512, 512);
  gemm_bt<64,4,2><<<dim3(16, 32), 256, 0, stream>>>(attn_o, 1024, w_dca_out, 1024, dca_out_b, fo, 1024, fo, 1024, 1024);

  ln_k<<<dim3(4096), 256, 0, stream>>>(fo, dn3_s, dn3_b, ln_buf);
  gemm_bt<128,2,1><<<dim3(32, 32), 256, 0, stream>>>(ln_buf, 1024, w_dff1, 1024, dff1_b, nullptr, 0, ffh, 4096, 1024);
  gemm_bt<64,4,2><<<dim3(16, 32), 256, 0, stream>>>(ffh, 4096, w_dff2, 4096, dff2_b, fo, 1024, fo, 1024, 4096);
}

// Round 4
// 702.498 us; speedup vs baseline: 1.0053x; 1.0032x over previous
//
#include <hip/hip_runtime.h>

using u16 = unsigned short;

typedef float f32x4 __attribute__((ext_vector_type(4)));
typedef __bf16 bf16x8v __attribute__((ext_vector_type(8)));
typedef bf16x8v bf16x8 __attribute__((may_alias));
typedef u16 u16x8v __attribute__((ext_vector_type(8)));
typedef u16x8v u16x8 __attribute__((may_alias));
typedef u16 u16x4v __attribute__((ext_vector_type(4)));
typedef u16x4v u16x4 __attribute__((may_alias));
typedef float f32x4v __attribute__((ext_vector_type(4)));
typedef f32x4v float4a __attribute__((may_alias));

#define GPTR(p) ((__attribute__((address_space(1))) void*)(p))
#define LPTR(p) ((__attribute__((address_space(3))) void*)(p))

__device__ __forceinline__ u16 f2bf(float f) {
  unsigned u = __builtin_bit_cast(unsigned, f);
  u += 0x7FFFu + ((u >> 16) & 1u);
  return (u16)(u >> 16);
}

__device__ __forceinline__ f32x4 mfma16(bf16x8 a, bf16x8 b, f32x4 c) {
  return __builtin_amdgcn_mfma_f32_16x16x32_bf16(a, b, c, 0, 0, 0);
}

// ---------------- fp32 -> bf16 convert ----------------
__global__ __launch_bounds__(256) void cvt_bf16(const float* __restrict__ in,
                                                u16* __restrict__ out, int n4) {
  int i = blockIdx.x * 256 + threadIdx.x;
  if (i < n4) {
    float4a v = ((const float4a*)in)[i];
    u16x4 o;
    o[0] = f2bf(v[0]); o[1] = f2bf(v[1]); o[2] = f2bf(v[2]); o[3] = f2bf(v[3]);
    ((u16x4*)out)[i] = o;
  }
}

// ---------------- LayerNorm (D=1024), fp32 in -> bf16 out ----------------
__global__ __launch_bounds__(256) void ln_k(const float* __restrict__ x,
                                            const float* __restrict__ sc,
                                            const float* __restrict__ bi,
                                            u16* __restrict__ out) {
  const int row = blockIdx.x, tid = threadIdx.x;
  float4a v = ((const float4a*)(x + (size_t)row * 1024))[tid];
  float s1 = v[0] + v[1] + v[2] + v[3];
  float s2 = v[0]*v[0] + v[1]*v[1] + v[2]*v[2] + v[3]*v[3];
#pragma unroll
  for (int off = 32; off; off >>= 1) { s1 += __shfl_xor(s1, off); s2 += __shfl_xor(s2, off); }
  __shared__ float red[8];
  if ((tid & 63) == 0) { red[tid >> 6] = s1; red[4 + (tid >> 6)] = s2; }
  __syncthreads();
  s1 = red[0] + red[1] + red[2] + red[3];
  s2 = red[4] + red[5] + red[6] + red[7];
  const float mean = s1 * (1.f / 1024.f);
  const float rstd = rsqrtf(s2 * (1.f / 1024.f) - mean * mean + 1e-6f);
  float4a s4 = ((const float4a*)sc)[tid];
  float4a b4 = ((const float4a*)bi)[tid];
  u16x4 o;
#pragma unroll
  for (int j = 0; j < 4; j++) o[j] = f2bf((v[j] - mean) * rstd * s4[j] + b4[j]);
  ((u16x4*)(out + (size_t)row * 1024))[tid] = o;
}

// ---------------- GEMM: out = epi(A[M,K] * W[N,K]^T + bias [+ C0]) ----------------
// EPI: 0 = bf16 out, bias;  1 = bf16 out, bias, relu;  2 = fp32 out, bias + C0 residual
template <int BN_T, int MW, int EPI>
__global__ __launch_bounds__(256) void gemm_bt(
    const u16* __restrict__ A, int lda,
    const u16* __restrict__ W, int ldw,
    const float* __restrict__ bias,
    const float* __restrict__ C0, int ldc0,
    void* __restrict__ outv, int ldo, int K) {
  constexpr int BM = 128, BK = 64;
  constexpr int NW = 4 / MW;
  constexpr int FM = BM / MW / 16;
  constexpr int FN = BN_T / NW / 16;
  constexpr int RA = (BM * BK * 2) / 4096;
  constexpr int RB = (BN_T * BK * 2) / 4096;
  __shared__ alignas(16) u16 As[BM * BK];
  __shared__ alignas(16) u16 Bs[BN_T * BK];
  const int tid = threadIdx.x, lane = tid & 63, wv = tid >> 6;
  const int bm = blockIdx.y * BM, bn = blockIdx.x * BN_T;
  const int wr = (wv / NW) * (BM / MW);
  const int wc = (wv % NW) * (BN_T / NW);
  const int la = lane & 15, lk = (lane >> 4) * 8;
  const int srow = wv * 8 + (lane >> 3), scol = (lane & 7) * 8;
  const u16* gA = A + (size_t)(bm + srow) * lda + scol;
  const u16* gB = W + (size_t)(bn + srow) * ldw + scol;
  u16* lA = As + (wv * 8) * BK;  // wave-uniform LDS base; HW scatters lane*16B
  u16* lB = Bs + (wv * 8) * BK;

  f32x4 acc[FM][FN] = {};

  for (int k0 = 0; k0 < K; k0 += BK) {
    __syncthreads();
#pragma unroll
    for (int r = 0; r < RA; r++)
      __builtin_amdgcn_global_load_lds(GPTR(gA + (size_t)r * 32 * lda + k0),
                                       LPTR(lA + r * 32 * BK), 16, 0, 0);
#pragma unroll
    for (int r = 0; r < RB; r++)
      __builtin_amdgcn_global_load_lds(GPTR(gB + (size_t)r * 32 * ldw + k0),
                                       LPTR(lB + r * 32 * BK), 16, 0, 0);
    __syncthreads();
#pragma unroll
    for (int kk = 0; kk < BK; kk += 32) {
      bf16x8 af[FM], bfr[FN];
#pragma unroll
      for (int m = 0; m < FM; m++) af[m] = *(const bf16x8*)&As[(wr + m * 16 + la) * BK + kk + lk];
#pragma unroll
      for (int n = 0; n < FN; n++) bfr[n] = *(const bf16x8*)&Bs[(wc + n * 16 + la) * BK + kk + lk];
#pragma unroll
      for (int m = 0; m < FM; m++)
#pragma unroll
        for (int n = 0; n < FN; n++)
          acc[m][n] = mfma16(af[m], bfr[n], acc[m][n]);
    }
  }
  float bv[FN];
#pragma unroll
  for (int n = 0; n < FN; n++) bv[n] = bias[bn + wc + n * 16 + la];
#pragma unroll
  for (int m = 0; m < FM; m++) {
#pragma unroll
    for (int j = 0; j < 4; j++) {
      const int row = bm + wr + m * 16 + (lane >> 4) * 4 + j;
#pragma unroll
      for (int n = 0; n < FN; n++) {
        const int col = bn + wc + n * 16 + la;
        float v = acc[m][n][j] + bv[n];
        if constexpr (EPI == 1) v = fmaxf(v, 0.f);
        if constexpr (EPI == 2) {
          ((float*)outv)[(size_t)row * ldo + col] = v + C0[(size_t)row * ldc0 + col];
        } else {
          ((u16*)outv)[(size_t)row * ldo + col] = f2bf(v);
        }
      }
    }
  }
}

// ---------------- fused attention (flash-style), hd=64, H=16 ----------------
// grid: (Tq/64, B*H); block 256 (4 waves, 16 q-rows each). KV tile = 128.
template <bool CAUSAL>
__global__ __launch_bounds__(256) void attn_k(
    const u16* __restrict__ Qb, int ldq,
    const u16* __restrict__ Kb, int ldk,
    const u16* __restrict__ Vb, int ldv,
    const float* __restrict__ rel,   // [256,16]
    u16* __restrict__ Ob, int ldo,
    int Tq, int Tk) {
  __shared__ alignas(16) u16 Ks[128][72];     // +8 pad: 2-way banks on frag reads
  __shared__ alignas(16) u16 Vt[64][136];     // V transposed [d][kv], +8 pad
  __shared__ alignas(16) u16 Ps[4][16][136];  // per-wave P tile [q][kv], +8 pad
  __shared__ float biasl[256];
  const int tid = threadIdx.x, lane = tid & 63, w = tid >> 6;
  const int b = blockIdx.y >> 4, h = blockIdx.y & 15;
  const int q0 = blockIdx.x * 64;
  const int la = lane & 15, lg = lane >> 4;

  biasl[tid] = rel[tid * 16 + h];

  const int qr0 = q0 + w * 16;
  const u16* qp = Qb + (size_t)(b * Tq + qr0 + la) * ldq + h * 64 + lg * 8;
  const bf16x8 qf0 = *(const bf16x8*)qp;
  const bf16x8 qf1 = *(const bf16x8*)(qp + 32);

  float m[4], sm[4];
  f32x4 acc[4] = {};
#pragma unroll
  for (int j = 0; j < 4; j++) { m[j] = -1e30f; sm[j] = 0.f; }

  const int kv_end = CAUSAL ? (q0 + 64) : Tk;
  const int srow = tid >> 3, scol = (tid & 7) * 8;
  for (int kv0 = 0; kv0 < kv_end; kv0 += 128) {
    __syncthreads();
#pragma unroll
    for (int r = 0; r < 4; r++) {
      const int row = r * 32 + srow;
      const size_t gr = (size_t)(b * Tk + kv0 + row);
      *(u16x8*)&Ks[row][scol] = *(const u16x8*)&Kb[gr * ldk + h * 64 + scol];
      u16x8 vv = *(const u16x8*)&Vb[gr * ldv + h * 64 + scol];
#pragma unroll
      for (int j = 0; j < 8; j++) Vt[scol + j][row] = vv[j];
    }
    __syncthreads();

    f32x4 s[8];
#pragma unroll
    for (int kvt = 0; kvt < 8; kvt++) {
      const bf16x8 kf0 = *(const bf16x8*)&Ks[kvt * 16 + la][lg * 8];
      const bf16x8 kf1 = *(const bf16x8*)&Ks[kvt * 16 + la][32 + lg * 8];
      f32x4 t = {};
      t = mfma16(qf0, kf0, t);
      t = mfma16(qf1, kf1, t);
      const int kc = kv0 + kvt * 16 + la;
#pragma unroll
      for (int j = 0; j < 4; j++) {
        const int qr = qr0 + lg * 4 + j;
        const int rp = kc - qr;
        const int bucket = rp < 0 ? (rp > -127 ? -rp : 127) : (rp < 127 ? rp : 127) + 128;
        float sv = t[j] * 0.125f + biasl[bucket];
        if (CAUSAL && kc > qr) sv = -1e30f;
        s[kvt][j] = sv;
      }
    }
    float alpha[4];
#pragma unroll
    for (int j = 0; j < 4; j++) {
      float tm = s[0][j];
#pragma unroll
      for (int kvt = 1; kvt < 8; kvt++) tm = fmaxf(tm, s[kvt][j]);
#pragma unroll
      for (int off = 1; off < 16; off <<= 1) tm = fmaxf(tm, __shfl_xor(tm, off));
      const float mn = fmaxf(m[j], tm);
      alpha[j] = __expf(m[j] - mn);
      m[j] = mn;
      float r = 0.f;
#pragma unroll
      for (int kvt = 0; kvt < 8; kvt++) {
        const float p = __expf(s[kvt][j] - mn);
        s[kvt][j] = p;
        r += p;
      }
#pragma unroll
      for (int off = 1; off < 16; off <<= 1) r += __shfl_xor(r, off);
      sm[j] = sm[j] * alpha[j] + r;
    }
#pragma unroll
    for (int kvt = 0; kvt < 8; kvt++)
#pragma unroll
      for (int j = 0; j < 4; j++)
        Ps[w][lg * 4 + j][kvt * 16 + la] = f2bf(s[kvt][j]);
#pragma unroll
    for (int n = 0; n < 4; n++)
#pragma unroll
      for (int j = 0; j < 4; j++)
        acc[n][j] *= alpha[j];
#pragma unroll
    for (int kq = 0; kq < 4; kq++) {
      const bf16x8 pf = *(const bf16x8*)&Ps[w][la][kq * 32 + lg * 8];
#pragma unroll
      for (int n = 0; n < 4; n++) {
        const bf16x8 vf = *(const bf16x8*)&Vt[n * 16 + la][kq * 32 + lg * 8];
        acc[n] = mfma16(pf, vf, acc[n]);
      }
    }
  }
#pragma unroll
  for (int n = 0; n < 4; n++)
#pragma unroll
    for (int j = 0; j < 4; j++) {
      const int qr = qr0 + lg * 4 + j;
      Ob[(size_t)(b * Tq + qr) * ldo + h * 64 + n * 16 + la] = f2bf(acc[n][j] / sm[j]);
    }
}

extern "C" void kernel_launch(void* const* d_in, const int* in_sizes, int n_in,
                              void* d_out, int out_size, void* d_ws, size_t ws_size,
                              hipStream_t stream) {
  (void)in_sizes; (void)n_in; (void)out_size; (void)ws_size;
  const float* src       = (const float*)d_in[0];
  const float* tgt       = (const float*)d_in[1];
  const float* enc_in_w  = (const float*)d_in[2];
  const float* enc_in_b  = (const float*)d_in[3];
  const float* enc_out_w = (const float*)d_in[4];
  const float* enc_out_b = (const float*)d_in[5];
  const float* enc_ff1_w = (const float*)d_in[6];
  const float* enc_ff1_b = (const float*)d_in[7];
  const float* enc_ff2_w = (const float*)d_in[8];
  const float* enc_ff2_b = (const float*)d_in[9];
  const float* enc_n1_s  = (const float*)d_in[10];
  const float* enc_n1_b  = (const float*)d_in[11];
  const float* enc_n2_s  = (const float*)d_in[12];
  const float* enc_n2_b  = (const float*)d_in[13];
  const float* enc_rel   = (const float*)d_in[14];
  const float* dsa_in_w  = (const float*)d_in[15];
  const float* dsa_in_b  = (const float*)d_in[16];
  const float* dsa_out_w = (const float*)d_in[17];
  const float* dsa_out_b = (const float*)d_in[18];
  const float* dca_in_w  = (const float*)d_in[19];
  const float* dca_in_b  = (const float*)d_in[20];
  const float* dca_out_w = (const float*)d_in[21];
  const float* dca_out_b = (const float*)d_in[22];
  const float* dff1_w    = (const float*)d_in[23];
  const float* dff1_b    = (const float*)d_in[24];
  const float* dff2_w    = (const float*)d_in[25];
  const float* dff2_b    = (const float*)d_in[26];
  const float* dn1_s     = (const float*)d_in[27];
  const float* dn1_b     = (const float*)d_in[28];
  const float* dn2_s     = (const float*)d_in[29];
  const float* dn2_b     = (const float*)d_in[30];
  const float* dn3_s     = (const float*)d_in[31];
  const float* dn3_b     = (const float*)d_in[32];
  const float* drel_s    = (const float*)d_in[33];
  const float* drel_c    = (const float*)d_in[34];
  float* fo = (float*)d_out;

  // workspace layout (120 MB total)
  char* w8 = (char*)d_ws;
  float* x_ws  = (float*)(w8 + 0);          // 16,777,216 B  encoder residual
  u16* ln_buf  = (u16*)(w8 + 16777216);     //  8,388,608 B
  u16* qkv     = (u16*)(w8 + 25165824);     // 25,165,824 B
  u16* attn_o  = (u16*)(w8 + 50331648);     //  8,388,608 B
  u16* ffh     = qkv;                       // 33,554,432 B  (aliases qkv+attn_o)
  u16* memb    = (u16*)(w8 + 58720256);     //  8,388,608 B  bf16 encoder memory
  u16* wb      = (u16*)(w8 + 67108864);     // 58,720,256 B  bf16 weights

  u16* w_enc_in  = wb;
  u16* w_enc_out = wb + 3145728;
  u16* w_enc_f1  = wb + 4194304;
  u16* w_enc_f2  = wb + 8388608;
  u16* w_dsa_in  = wb + 12582912;
  u16* w_dsa_out = wb + 15728640;
  u16* w_dca_in  = wb + 16777216;
  u16* w_dca_out = wb + 19922944;
  u16* w_dff1    = wb + 20971520;
  u16* w_dff2    = wb + 25165824;

#define CVT(sp, dp, n) cvt_bf16<<<dim3((n) / 1024), 256, 0, stream>>>(sp, dp, (n) / 4)
  CVT(enc_in_w,  w_enc_in,  3145728);
  CVT(enc_out_w, w_enc_out, 1048576);
  CVT(enc_ff1_w, w_enc_f1,  4194304);
  CVT(enc_ff2_w, w_enc_f2,  4194304);
  CVT(dsa_in_w,  w_dsa_in,  3145728);
  CVT(dsa_out_w, w_dsa_out, 1048576);
  CVT(dca_in_w,  w_dca_in,  3145728);
  CVT(dca_out_w, w_dca_out, 1048576);
  CVT(dff1_w,    w_dff1,    4194304);
  CVT(dff2_w,    w_dff2,    4194304);
#undef CVT

  // ---------------- encoder layer ----------------
  ln_k<<<dim3(4096), 256, 0, stream>>>(src, enc_n1_s, enc_n1_b, ln_buf);
  gemm_bt<128,2,0><<<dim3(24, 32), 256, 0, stream>>>(ln_buf, 1024, w_enc_in, 1024, enc_in_b, nullptr, 0, qkv, 3072, 1024);
  attn_k<false><<<dim3(8, 128), 256, 0, stream>>>(qkv, 3072, qkv + 1024, 3072, qkv + 2048, 3072, enc_rel, attn_o, 1024, 512, 512);
  gemm_bt<64,4,2><<<dim3(16, 32), 256, 0, stream>>>(attn_o, 1024, w_enc_out, 1024, enc_out_b, src, 1024, x_ws, 1024, 1024);
  ln_k<<<dim3(4096), 256, 0, stream>>>(x_ws, enc_n2_s, enc_n2_b, ln_buf);
  gemm_bt<128,2,1><<<dim3(32, 32), 256, 0, stream>>>(ln_buf, 1024, w_enc_f1, 1024, enc_ff1_b, nullptr, 0, ffh, 4096, 1024);
  gemm_bt<64,4,2><<<dim3(16, 32), 256, 0, stream>>>(ffh, 4096, w_enc_f2, 4096, enc_ff2_b, x_ws, 1024, x_ws, 1024, 4096);
  cvt_bf16<<<dim3(4096), 256, 0, stream>>>(x_ws, memb, 1048576);

  // ---------------- decoder layer ----------------
  ln_k<<<dim3(4096), 256, 0, stream>>>(tgt, dn1_s, dn1_b, ln_buf);
  gemm_bt<128,2,0><<<dim3(24, 32), 256, 0, stream>>>(ln_buf, 1024, w_dsa_in, 1024, dsa_in_b, nullptr, 0, qkv, 3072, 1024);
  attn_k<true><<<dim3(8, 128), 256, 0, stream>>>(qkv, 3072, qkv + 1024, 3072, qkv + 2048, 3072, drel_s, attn_o, 1024, 512, 512);
  gemm_bt<64,4,2><<<dim3(16, 32), 256, 0, stream>>>(attn_o, 1024, w_dsa_out, 1024, dsa_out_b, tgt, 1024, fo, 1024, 1024);

  ln_k<<<dim3(4096), 256, 0, stream>>>(fo, dn2_s, dn2_b, ln_buf);
  gemm_bt<64,4,0><<<dim3(16, 32), 256, 0, stream>>>(ln_buf, 1024, w_dca_in, 1024, dca_in_b, nullptr, 0, qkv, 3072, 1024);
  gemm_bt<128,2,0><<<dim3(16, 32), 256, 0, stream>>>(memb, 1024, w_dca_in + 1048576, 1024, dca_in_b + 1024, nullptr, 0, qkv + 1024, 3072, 1024);
  attn_k<false><<<dim3(8, 128), 256, 0, stream>>>(qkv, 3072, qkv + 1024, 3072, qkv + 2048, 3072, drel_c, attn_o, 1024, 512, 512);
  gemm_bt<64,4,2><<<dim3(16, 32), 256, 0, stream>>>(attn_o, 1024, w_dca_out, 1024, dca_out_b, fo, 1024, fo, 1024, 1024);

  ln_k<<<dim3(4096), 256, 0, stream>>>(fo, dn3_s, dn3_b, ln_buf);
  gemm_bt<128,2,1><<<dim3(32, 32), 256, 0, stream>>>(ln_buf, 1024, w_dff1, 1024, dff1_b, nullptr, 0, ffh, 4096, 1024);
  gemm_bt<64,4,2><<<dim3(16, 32), 256, 0, stream>>>(ffh, 4096, w_dff2, 4096, dff2_b, fo, 1024, fo, 1024, 4096);
}

// Round 5
// 674.135 us; speedup vs baseline: 1.0476x; 1.0421x over previous
//
#include <hip/hip_runtime.h>

using u16 = unsigned short;

typedef float f32x4 __attribute__((ext_vector_type(4)));
typedef __bf16 bf16x8v __attribute__((ext_vector_type(8)));
typedef bf16x8v bf16x8 __attribute__((may_alias));
typedef u16 u16x8v __attribute__((ext_vector_type(8)));
typedef u16x8v u16x8 __attribute__((may_alias));
typedef u16 u16x4v __attribute__((ext_vector_type(4)));
typedef u16x4v u16x4 __attribute__((may_alias));
typedef float f32x4v __attribute__((ext_vector_type(4)));
typedef f32x4v float4a __attribute__((may_alias));

#define GPTR(p) ((__attribute__((address_space(1))) void*)(p))
#define LPTR(p) ((__attribute__((address_space(3))) void*)(p))

__device__ __forceinline__ u16 f2bf(float f) {
  unsigned u = __builtin_bit_cast(unsigned, f);
  u += 0x7FFFu + ((u >> 16) & 1u);
  return (u16)(u >> 16);
}

__device__ __forceinline__ f32x4 mfma16(bf16x8 a, bf16x8 b, f32x4 c) {
  return __builtin_amdgcn_mfma_f32_16x16x32_bf16(a, b, c, 0, 0, 0);
}

// vmcnt(0) drain + raw barrier (no compiler-forced lgkm drain), pinned.
#define WAITBAR()                                          \
  do {                                                     \
    asm volatile("s_waitcnt vmcnt(0)" ::: "memory");       \
    __builtin_amdgcn_s_barrier();                          \
    __builtin_amdgcn_sched_barrier(0);                     \
  } while (0)

// ---------------- fp32 -> bf16 convert ----------------
__global__ __launch_bounds__(256) void cvt_bf16(const float* __restrict__ in,
                                                u16* __restrict__ out, int n4) {
  int i = blockIdx.x * 256 + threadIdx.x;
  if (i < n4) {
    float4a v = ((const float4a*)in)[i];
    u16x4 o;
    o[0] = f2bf(v[0]); o[1] = f2bf(v[1]); o[2] = f2bf(v[2]); o[3] = f2bf(v[3]);
    ((u16x4*)out)[i] = o;
  }
}

// ---------------- LayerNorm (D=1024), fp32 in -> bf16 out ----------------
__global__ __launch_bounds__(256) void ln_k(const float* __restrict__ x,
                                            const float* __restrict__ sc,
                                            const float* __restrict__ bi,
                                            u16* __restrict__ out) {
  const int row = blockIdx.x, tid = threadIdx.x;
  float4a v = ((const float4a*)(x + (size_t)row * 1024))[tid];
  float s1 = v[0] + v[1] + v[2] + v[3];
  float s2 = v[0]*v[0] + v[1]*v[1] + v[2]*v[2] + v[3]*v[3];
#pragma unroll
  for (int off = 32; off; off >>= 1) { s1 += __shfl_xor(s1, off); s2 += __shfl_xor(s2, off); }
  __shared__ float red[8];
  if ((tid & 63) == 0) { red[tid >> 6] = s1; red[4 + (tid >> 6)] = s2; }
  __syncthreads();
  s1 = red[0] + red[1] + red[2] + red[3];
  s2 = red[4] + red[5] + red[6] + red[7];
  const float mean = s1 * (1.f / 1024.f);
  const float rstd = rsqrtf(s2 * (1.f / 1024.f) - mean * mean + 1e-6f);
  float4a s4 = ((const float4a*)sc)[tid];
  float4a b4 = ((const float4a*)bi)[tid];
  u16x4 o;
#pragma unroll
  for (int j = 0; j < 4; j++) o[j] = f2bf((v[j] - mean) * rstd * s4[j] + b4[j]);
  ((u16x4*)(out + (size_t)row * 1024))[tid] = o;
}

// ---------------- GEMM: out = epi(A[M,K] * W[N,K]^T + bias [+ C0]) ----------------
// EPI: 0 = bf16 out, bias;  1 = bf16 out, bias, relu;  2 = fp32 out, bias + C0 residual
// PF:  0 = single-buffer 2-barrier loop; 1 = prefetch double-buffer (K % 128 == 0)
// LDS staged via global_load_lds with T2 read-swizzle realized by pre-swizzling the
// global SOURCE column (rule 21): physical slot p of row r holds logical slot p^(r&7).
template <int BN_T, int MW, int EPI, int PF>
__global__ __launch_bounds__(256) void gemm_bt(
    const u16* __restrict__ A, int lda,
    const u16* __restrict__ W, int ldw,
    const float* __restrict__ bias,
    const float* __restrict__ C0, int ldc0,
    void* __restrict__ outv, int ldo, int K) {
  constexpr int BM = 128, BK = 64;
  constexpr int NW = 4 / MW;
  constexpr int FM = BM / MW / 16;
  constexpr int FN = BN_T / NW / 16;
  constexpr int RA = (BM * BK * 2) / 4096;
  constexpr int RB = (BN_T * BK * 2) / 4096;
  constexpr int NB = PF ? 2 : 1;
  __shared__ alignas(16) u16 As[NB][BM * BK];
  __shared__ alignas(16) u16 Bs[NB][BN_T * BK];
  const int tid = threadIdx.x, lane = tid & 63, wv = tid >> 6;

  // T1: bijective XCD-chunked block swizzle (m204). Consecutive wg = consecutive
  // N-tiles of one M-row -> share the A panel within one XCD's L2.
  const int gx = gridDim.x;
  const int nwg = gx * gridDim.y;
  const int orig = blockIdx.y * gx + blockIdx.x;
  const int qq = nwg >> 3, rr = nwg & 7;
  const int xcd = orig & 7, idx = orig >> 3;
  const int wg = (xcd < rr ? xcd * (qq + 1) : rr * (qq + 1) + (xcd - rr) * qq) + idx;
  const int bm = (wg / gx) * BM, bn = (wg % gx) * BN_T;

  const int wr = (wv / NW) * (BM / MW);
  const int wc = (wv % NW) * (BN_T / NW);
  const int la = lane & 15, lg = lane >> 4;
  const int r7 = la & 7;
  const int srow = wv * 8 + (lane >> 3);
  const int scol = ((lane & 7) ^ (lane >> 3)) << 3;  // pre-swizzled source slot
  const u16* gA = A + (size_t)(bm + srow) * lda + scol;
  const u16* gB = W + (size_t)(bn + srow) * ldw + scol;

  f32x4 acc[FM][FN] = {};

#define STAGE(buf, k0)                                                              \
  do {                                                                              \
    _Pragma("unroll")                                                               \
    for (int r = 0; r < RA; r++)                                                    \
      __builtin_amdgcn_global_load_lds(GPTR(gA + (size_t)r * 32 * lda + (k0)),      \
                                       LPTR(&As[buf][(wv * 8 + r * 32) * BK]), 16, 0, 0); \
    _Pragma("unroll")                                                               \
    for (int r = 0; r < RB; r++)                                                    \
      __builtin_amdgcn_global_load_lds(GPTR(gB + (size_t)r * 32 * ldw + (k0)),      \
                                       LPTR(&Bs[buf][(wv * 8 + r * 32) * BK]), 16, 0, 0); \
  } while (0)

#define COMPUTE(buf)                                                                \
  do {                                                                              \
    _Pragma("unroll")                                                               \
    for (int kk = 0; kk < BK; kk += 32) {                                           \
      const int off = ((((kk >> 3) + lg) ^ r7) << 3);                               \
      bf16x8 af[FM], bfr[FN];                                                       \
      _Pragma("unroll")                                                             \
      for (int m = 0; m < FM; m++)                                                  \
        af[m] = *(const bf16x8*)&As[buf][(wr + m * 16 + la) * BK + off];            \
      _Pragma("unroll")                                                             \
      for (int n = 0; n < FN; n++)                                                  \
        bfr[n] = *(const bf16x8*)&Bs[buf][(wc + n * 16 + la) * BK + off];           \
      _Pragma("unroll")                                                             \
      for (int m = 0; m < FM; m++)                                                  \
        _Pragma("unroll")                                                           \
        for (int n = 0; n < FN; n++)                                                \
          acc[m][n] = mfma16(af[m], bfr[n], acc[m][n]);                             \
    }                                                                               \
  } while (0)

  if constexpr (PF) {
    // T3-minimum prefetch pipeline, unrolled x2 for compile-time buffer indices.
    STAGE(0, 0);
    WAITBAR();
    for (int k0 = 0; k0 < K; k0 += 2 * BK) {
      STAGE(1, k0 + BK);
      COMPUTE(0);
      WAITBAR();
      if (k0 + 2 * BK < K) STAGE(0, k0 + 2 * BK);
      COMPUTE(1);
      WAITBAR();
    }
  } else {
    for (int k0 = 0; k0 < K; k0 += BK) {
      __syncthreads();
      STAGE(0, k0);
      __syncthreads();
      COMPUTE(0);
    }
  }
#undef STAGE
#undef COMPUTE

  float bv[FN];
#pragma unroll
  for (int n = 0; n < FN; n++) bv[n] = bias[bn + wc + n * 16 + la];
#pragma unroll
  for (int m = 0; m < FM; m++) {
#pragma unroll
    for (int j = 0; j < 4; j++) {
      const int row = bm + wr + m * 16 + (lane >> 4) * 4 + j;
#pragma unroll
      for (int n = 0; n < FN; n++) {
        const int col = bn + wc + n * 16 + la;
        float v = acc[m][n][j] + bv[n];
        if constexpr (EPI == 1) v = fmaxf(v, 0.f);
        if constexpr (EPI == 2) {
          ((float*)outv)[(size_t)row * ldo + col] = v + C0[(size_t)row * ldc0 + col];
        } else {
          ((u16*)outv)[(size_t)row * ldo + col] = f2bf(v);
        }
      }
    }
  }
}

// ---------------- fused attention (flash-style), hd=64, H=16 ----------------
template <bool CAUSAL>
__global__ __launch_bounds__(256) void attn_k(
    const u16* __restrict__ Qb, int ldq,
    const u16* __restrict__ Kb, int ldk,
    const u16* __restrict__ Vb, int ldv,
    const float* __restrict__ rel,   // [256,16]
    u16* __restrict__ Ob, int ldo,
    int Tq, int Tk) {
  __shared__ alignas(16) u16 Ks[128][72];
  __shared__ alignas(16) u16 Vt[64][136];
  __shared__ alignas(16) u16 Ps[4][16][136];
  __shared__ float biasl[256];
  const int tid = threadIdx.x, lane = tid & 63, w = tid >> 6;
  const int b = blockIdx.y >> 4, h = blockIdx.y & 15;
  const int q0 = blockIdx.x * 64;
  const int la = lane & 15, lg = lane >> 4;

  biasl[tid] = rel[tid * 16 + h];

  const int qr0 = q0 + w * 16;
  const u16* qp = Qb + (size_t)(b * Tq + qr0 + la) * ldq + h * 64 + lg * 8;
  const bf16x8 qf0 = *(const bf16x8*)qp;
  const bf16x8 qf1 = *(const bf16x8*)(qp + 32);

  float m[4], sm[4];
  f32x4 acc[4] = {};
#pragma unroll
  for (int j = 0; j < 4; j++) { m[j] = -1e30f; sm[j] = 0.f; }

  const int kv_end = CAUSAL ? (q0 + 64) : Tk;
  const int srow = tid >> 3, scol = (tid & 7) * 8;
  for (int kv0 = 0; kv0 < kv_end; kv0 += 128) {
    __syncthreads();
#pragma unroll
    for (int r = 0; r < 4; r++) {
      const int row = r * 32 + srow;
      const size_t gr = (size_t)(b * Tk + kv0 + row);
      *(u16x8*)&Ks[row][scol] = *(const u16x8*)&Kb[gr * ldk + h * 64 + scol];
      u16x8 vv = *(const u16x8*)&Vb[gr * ldv + h * 64 + scol];
#pragma unroll
      for (int j = 0; j < 8; j++) Vt[scol + j][row] = vv[j];
    }
    __syncthreads();

    f32x4 s[8];
#pragma unroll
    for (int kvt = 0; kvt < 8; kvt++) {
      const bf16x8 kf0 = *(const bf16x8*)&Ks[kvt * 16 + la][lg * 8];
      const bf16x8 kf1 = *(const bf16x8*)&Ks[kvt * 16 + la][32 + lg * 8];
      f32x4 t = {};
      t = mfma16(qf0, kf0, t);
      t = mfma16(qf1, kf1, t);
      const int kc = kv0 + kvt * 16 + la;
#pragma unroll
      for (int j = 0; j < 4; j++) {
        const int qr = qr0 + lg * 4 + j;
        const int rp = kc - qr;
        const int bucket = rp < 0 ? (rp > -127 ? -rp : 127) : (rp < 127 ? rp : 127) + 128;
        float sv = t[j] * 0.125f + biasl[bucket];
        if (CAUSAL && kc > qr) sv = -1e30f;
        s[kvt][j] = sv;
      }
    }
    float alpha[4];
#pragma unroll
    for (int j = 0; j < 4; j++) {
      float tm = s[0][j];
#pragma unroll
      for (int kvt = 1; kvt < 8; kvt++) tm = fmaxf(tm, s[kvt][j]);
#pragma unroll
      for (int off = 1; off < 16; off <<= 1) tm = fmaxf(tm, __shfl_xor(tm, off));
      const float mn = fmaxf(m[j], tm);
      alpha[j] = __expf(m[j] - mn);
      m[j] = mn;
      float r = 0.f;
#pragma unroll
      for (int kvt = 0; kvt < 8; kvt++) {
        const float p = __expf(s[kvt][j] - mn);
        s[kvt][j] = p;
        r += p;
      }
#pragma unroll
      for (int off = 1; off < 16; off <<= 1) r += __shfl_xor(r, off);
      sm[j] = sm[j] * alpha[j] + r;
    }
#pragma unroll
    for (int kvt = 0; kvt < 8; kvt++)
#pragma unroll
      for (int j = 0; j < 4; j++)
        Ps[w][lg * 4 + j][kvt * 16 + la] = f2bf(s[kvt][j]);
#pragma unroll
    for (int n = 0; n < 4; n++)
#pragma unroll
      for (int j = 0; j < 4; j++)
        acc[n][j] *= alpha[j];
#pragma unroll
    for (int kq = 0; kq < 4; kq++) {
      const bf16x8 pf = *(const bf16x8*)&Ps[w][la][kq * 32 + lg * 8];
#pragma unroll
      for (int n = 0; n < 4; n++) {
        const bf16x8 vf = *(const bf16x8*)&Vt[n * 16 + la][kq * 32 + lg * 8];
        acc[n] = mfma16(pf, vf, acc[n]);
      }
    }
  }
#pragma unroll
  for (int n = 0; n < 4; n++)
#pragma unroll
    for (int j = 0; j < 4; j++) {
      const int qr = qr0 + lg * 4 + j;
      Ob[(size_t)(b * Tq + qr) * ldo + h * 64 + n * 16 + la] = f2bf(acc[n][j] / sm[j]);
    }
}

extern "C" void kernel_launch(void* const* d_in, const int* in_sizes, int n_in,
                              void* d_out, int out_size, void* d_ws, size_t ws_size,
                              hipStream_t stream) {
  (void)in_sizes; (void)n_in; (void)out_size; (void)ws_size;
  const float* src       = (const float*)d_in[0];
  const float* tgt       = (const float*)d_in[1];
  const float* enc_in_w  = (const float*)d_in[2];
  const float* enc_in_b  = (const float*)d_in[3];
  const float* enc_out_w = (const float*)d_in[4];
  const float* enc_out_b = (const float*)d_in[5];
  const float* enc_ff1_w = (const float*)d_in[6];
  const float* enc_ff1_b = (const float*)d_in[7];
  const float* enc_ff2_w = (const float*)d_in[8];
  const float* enc_ff2_b = (const float*)d_in[9];
  const float* enc_n1_s  = (const float*)d_in[10];
  const float* enc_n1_b  = (const float*)d_in[11];
  const float* enc_n2_s  = (const float*)d_in[12];
  const float* enc_n2_b  = (const float*)d_in[13];
  const float* enc_rel   = (const float*)d_in[14];
  const float* dsa_in_w  = (const float*)d_in[15];
  const float* dsa_in_b  = (const float*)d_in[16];
  const float* dsa_out_w = (const float*)d_in[17];
  const float* dsa_out_b = (const float*)d_in[18];
  const float* dca_in_w  = (const float*)d_in[19];
  const float* dca_in_b  = (const float*)d_in[20];
  const float* dca_out_w = (const float*)d_in[21];
  const float* dca_out_b = (const float*)d_in[22];
  const float* dff1_w    = (const float*)d_in[23];
  const float* dff1_b    = (const float*)d_in[24];
  const float* dff2_w    = (const float*)d_in[25];
  const float* dff2_b    = (const float*)d_in[26];
  const float* dn1_s     = (const float*)d_in[27];
  const float* dn1_b     = (const float*)d_in[28];
  const float* dn2_s     = (const float*)d_in[29];
  const float* dn2_b     = (const float*)d_in[30];
  const float* dn3_s     = (const float*)d_in[31];
  const float* dn3_b     = (const float*)d_in[32];
  const float* drel_s    = (const float*)d_in[33];
  const float* drel_c    = (const float*)d_in[34];
  float* fo = (float*)d_out;

  // workspace layout (120 MB total)
  char* w8 = (char*)d_ws;
  float* x_ws  = (float*)(w8 + 0);          // 16,777,216 B  encoder residual
  u16* ln_buf  = (u16*)(w8 + 16777216);     //  8,388,608 B
  u16* qkv     = (u16*)(w8 + 25165824);     // 25,165,824 B
  u16* attn_o  = (u16*)(w8 + 50331648);     //  8,388,608 B
  u16* ffh     = qkv;                       // 33,554,432 B  (aliases qkv+attn_o)
  u16* memb    = (u16*)(w8 + 58720256);     //  8,388,608 B  bf16 encoder memory
  u16* wb      = (u16*)(w8 + 67108864);     // 58,720,256 B  bf16 weights

  u16* w_enc_in  = wb;
  u16* w_enc_out = wb + 3145728;
  u16* w_enc_f1  = wb + 4194304;
  u16* w_enc_f2  = wb + 8388608;
  u16* w_dsa_in  = wb + 12582912;
  u16* w_dsa_out = wb + 15728640;
  u16* w_dca_in  = wb + 16777216;
  u16* w_dca_out = wb + 19922944;
  u16* w_dff1    = wb + 20971520;
  u16* w_dff2    = wb + 25165824;

#define CVT(sp, dp, n) cvt_bf16<<<dim3((n) / 1024), 256, 0, stream>>>(sp, dp, (n) / 4)
  CVT(enc_in_w,  w_enc_in,  3145728);
  CVT(enc_out_w, w_enc_out, 1048576);
  CVT(enc_ff1_w, w_enc_f1,  4194304);
  CVT(enc_ff2_w, w_enc_f2,  4194304);
  CVT(dsa_in_w,  w_dsa_in,  3145728);
  CVT(dsa_out_w, w_dsa_out, 1048576);
  CVT(dca_in_w,  w_dca_in,  3145728);
  CVT(dca_out_w, w_dca_out, 1048576);
  CVT(dff1_w,    w_dff1,    4194304);
  CVT(dff2_w,    w_dff2,    4194304);
#undef CVT

  // ---------------- encoder layer ----------------
  ln_k<<<dim3(4096), 256, 0, stream>>>(src, enc_n1_s, enc_n1_b, ln_buf);
  gemm_bt<128,2,0,0><<<dim3(24, 32), 256, 0, stream>>>(ln_buf, 1024, w_enc_in, 1024, enc_in_b, nullptr, 0, qkv, 3072, 1024);
  attn_k<false><<<dim3(8, 128), 256, 0, stream>>>(qkv, 3072, qkv + 1024, 3072, qkv + 2048, 3072, enc_rel, attn_o, 1024, 512, 512);
  gemm_bt<64,4,2,1><<<dim3(16, 32), 256, 0, stream>>>(attn_o, 1024, w_enc_out, 1024, enc_out_b, src, 1024, x_ws, 1024, 1024);
  ln_k<<<dim3(4096), 256, 0, stream>>>(x_ws, enc_n2_s, enc_n2_b, ln_buf);
  gemm_bt<128,2,1,0><<<dim3(32, 32), 256, 0, stream>>>(ln_buf, 1024, w_enc_f1, 1024, enc_ff1_b, nullptr, 0, ffh, 4096, 1024);
  gemm_bt<64,4,2,1><<<dim3(16, 32), 256, 0, stream>>>(ffh, 4096, w_enc_f2, 4096, enc_ff2_b, x_ws, 1024, x_ws, 1024, 4096);
  cvt_bf16<<<dim3(4096), 256, 0, stream>>>(x_ws, memb, 1048576);

  // ---------------- decoder layer ----------------
  ln_k<<<dim3(4096), 256, 0, stream>>>(tgt, dn1_s, dn1_b, ln_buf);
  gemm_bt<128,2,0,0><<<dim3(24, 32), 256, 0, stream>>>(ln_buf, 1024, w_dsa_in, 1024, dsa_in_b, nullptr, 0, qkv, 3072, 1024);
  attn_k<true><<<dim3(8, 128), 256, 0, stream>>>(qkv, 3072, qkv + 1024, 3072, qkv + 2048, 3072, drel_s, attn_o, 1024, 512, 512);
  gemm_bt<64,4,2,1><<<dim3(16, 32), 256, 0, stream>>>(attn_o, 1024, w_dsa_out, 1024, dsa_out_b, tgt, 1024, fo, 1024, 1024);

  ln_k<<<dim3(4096), 256, 0, stream>>>(fo, dn2_s, dn2_b, ln_buf);
  gemm_bt<64,4,0,1><<<dim3(16, 32), 256, 0, stream>>>(ln_buf, 1024, w_dca_in, 1024, dca_in_b, nullptr, 0, qkv, 3072, 1024);
  gemm_bt<128,2,0,0><<<dim3(16, 32), 256, 0, stream>>>(memb, 1024, w_dca_in + 1048576, 1024, dca_in_b + 1024, nullptr, 0, qkv + 1024, 3072, 1024);
  attn_k<false><<<dim3(8, 128), 256, 0, stream>>>(qkv, 3072, qkv + 1024, 3072, qkv + 2048, 3072, drel_c, attn_o, 1024, 512, 512);
  gemm_bt<64,4,2,1><<<dim3(16, 32), 256, 0, stream>>>(attn_o, 1024, w_dca_out, 1024, dca_out_b, fo, 1024, fo, 1024, 1024);

  ln_k<<<dim3(4096), 256, 0, stream>>>(fo, dn3_s, dn3_b, ln_buf);
  gemm_bt<128,2,1,0><<<dim3(32, 32), 256, 0, stream>>>(ln_buf, 1024, w_dff1, 1024, dff1_b, nullptr, 0, ffh, 4096, 1024);
  gemm_bt<64,4,2,1><<<dim3(16, 32), 256, 0, stream>>>(ffh, 4096, w_dff2, 4096, dff2_b, fo, 1024, fo, 1024, 4096);
}

// Round 6
// 613.049 us; speedup vs baseline: 1.1520x; 1.0996x over previous
//
#include <hip/hip_runtime.h>

using u16 = unsigned short;

typedef float f32x4 __attribute__((ext_vector_type(4)));
typedef __bf16 bf16x8v __attribute__((ext_vector_type(8)));
typedef bf16x8v bf16x8 __attribute__((may_alias));
typedef u16 u16x8v __attribute__((ext_vector_type(8)));
typedef u16x8v u16x8 __attribute__((may_alias));
typedef u16 u16x4v __attribute__((ext_vector_type(4)));
typedef u16x4v u16x4 __attribute__((may_alias));
typedef float f32x4v __attribute__((ext_vector_type(4)));
typedef f32x4v float4a __attribute__((may_alias));

#define GPTR(p) ((__attribute__((address_space(1))) void*)(p))
#define LPTR(p) ((__attribute__((address_space(3))) void*)(p))

__device__ __forceinline__ u16 f2bf(float f) {
  unsigned u = __builtin_bit_cast(unsigned, f);
  u += 0x7FFFu + ((u >> 16) & 1u);
  return (u16)(u >> 16);
}

__device__ __forceinline__ f32x4 mfma16(bf16x8 a, bf16x8 b, f32x4 c) {
  return __builtin_amdgcn_mfma_f32_16x16x32_bf16(a, b, c, 0, 0, 0);
}

// ---------------- fused fp32 -> bf16 convert for ALL weights (1 dispatch) ----------------
struct Srcs { const float* s[10]; };

__global__ __launch_bounds__(256) void cvt_all(Srcs srcs, u16* __restrict__ dst) {
  // cumulative offsets in f32x4 units: enc_in, enc_out, enc_f1, enc_f2,
  // dsa_in, dsa_out, dca_in, dca_out, dff1, dff2
  constexpr int off[11] = {0, 786432, 1048576, 2097152, 3145728,
                           3932160, 4194304, 4980736, 5242880, 6291456, 7340032};
  const int i = blockIdx.x * 256 + threadIdx.x;
  int r = 0;
#pragma unroll
  for (int j = 1; j < 10; j++) r += (i >= off[j]);
  float4a v = ((const float4a*)srcs.s[r])[i - off[r]];
  u16x4 o;
  o[0] = f2bf(v[0]); o[1] = f2bf(v[1]); o[2] = f2bf(v[2]); o[3] = f2bf(v[3]);
  ((u16x4*)dst)[i] = o;
}

// ---------------- split-K reduce helpers ----------------
__global__ __launch_bounds__(256) void add_cvt(const float* __restrict__ a,
                                               const float* __restrict__ b,
                                               u16* __restrict__ o) {
  const int i = blockIdx.x * 256 + threadIdx.x;
  float4a va = ((const float4a*)a)[i];
  float4a vb = ((const float4a*)b)[i];
  u16x4 ov;
#pragma unroll
  for (int j = 0; j < 4; j++) ov[j] = f2bf(va[j] + vb[j]);
  ((u16x4*)o)[i] = ov;
}

__global__ __launch_bounds__(256) void add_f32(float* __restrict__ o,
                                               const float* __restrict__ b) {
  const int i = blockIdx.x * 256 + threadIdx.x;
  float4a vo = ((float4a*)o)[i];
  float4a vb = ((const float4a*)b)[i];
#pragma unroll
  for (int j = 0; j < 4; j++) vo[j] += vb[j];
  ((float4a*)o)[i] = vo;
}

// ---------------- LayerNorm (D=1024), fp32 in -> bf16 out ----------------
__global__ __launch_bounds__(256) void ln_k(const float* __restrict__ x,
                                            const float* __restrict__ sc,
                                            const float* __restrict__ bi,
                                            u16* __restrict__ out) {
  const int row = blockIdx.x, tid = threadIdx.x;
  float4a v = ((const float4a*)(x + (size_t)row * 1024))[tid];
  float s1 = v[0] + v[1] + v[2] + v[3];
  float s2 = v[0]*v[0] + v[1]*v[1] + v[2]*v[2] + v[3]*v[3];
#pragma unroll
  for (int off = 32; off; off >>= 1) { s1 += __shfl_xor(s1, off); s2 += __shfl_xor(s2, off); }
  __shared__ float red[8];
  if ((tid & 63) == 0) { red[tid >> 6] = s1; red[4 + (tid >> 6)] = s2; }
  __syncthreads();
  s1 = red[0] + red[1] + red[2] + red[3];
  s2 = red[4] + red[5] + red[6] + red[7];
  const float mean = s1 * (1.f / 1024.f);
  const float rstd = rsqrtf(s2 * (1.f / 1024.f) - mean * mean + 1e-6f);
  float4a s4 = ((const float4a*)sc)[tid];
  float4a b4 = ((const float4a*)bi)[tid];
  u16x4 o;
#pragma unroll
  for (int j = 0; j < 4; j++) o[j] = f2bf((v[j] - mean) * rstd * s4[j] + b4[j]);
  ((u16x4*)(out + (size_t)row * 1024))[tid] = o;
}

// ---------------- GEMM: out = epi(A[M,K] * W[N,K]^T + bias [+ C0]) ----------------
// EPI: 0 = bf16 out, bias;  1 = bf16 out, bias, relu;  2 = fp32 out, bias + C0 residual
//      3 = split-K: z==0 -> fp32 out = v+bias+C0; z==1 -> fp32 part = v (no bias)
// PF:  0 = single-buffer 2-barrier loop
//      1 = counted-vmcnt never-drain double-buffer (T3-minimum + T4)
// T2 read-swizzle realized by pre-swizzling the global SOURCE column (rule 21).
template <int BN_T, int MW, int EPI, int PF>
__global__ __launch_bounds__(256) void gemm_bt(
    const u16* __restrict__ A, int lda,
    const u16* __restrict__ W, int ldw,
    const float* __restrict__ bias,
    const float* __restrict__ C0, int ldc0,
    void* __restrict__ outv, int ldo, int K,
    float* __restrict__ part) {
  constexpr int BM = 128, BK = 64;
  constexpr int NW = 4 / MW;
  constexpr int FM = BM / MW / 16;
  constexpr int FN = BN_T / NW / 16;
  constexpr int RA = (BM * BK * 2) / 4096;
  constexpr int RB = (BN_T * BK * 2) / 4096;
  constexpr int NB = PF ? 2 : 1;
  __shared__ alignas(16) u16 As[NB][BM * BK];
  __shared__ alignas(16) u16 Bs[NB][BN_T * BK];
  const int tid = threadIdx.x, lane = tid & 63, wv = tid >> 6;
  const int kb = (EPI == 3) ? blockIdx.z * K : 0;

  // T1: bijective XCD-chunked block swizzle (m204), per z-plane.
  const int gx = gridDim.x;
  const int nwg = gx * gridDim.y;
  const int orig = blockIdx.y * gx + blockIdx.x;
  const int qq = nwg >> 3, rr = nwg & 7;
  const int xcd = orig & 7, idx = orig >> 3;
  const int wg = (xcd < rr ? xcd * (qq + 1) : rr * (qq + 1) + (xcd - rr) * qq) + idx;
  const int bm = (wg / gx) * BM, bn = (wg % gx) * BN_T;

  const int wr = (wv / NW) * (BM / MW);
  const int wc = (wv % NW) * (BN_T / NW);
  const int la = lane & 15, lg = lane >> 4;
  const int r7 = la & 7;
  const int srow = wv * 8 + (lane >> 3);
  const int scol = ((lane & 7) ^ (lane >> 3)) << 3;  // pre-swizzled source slot
  const u16* gA = A + (size_t)(bm + srow) * lda + scol;
  const u16* gB = W + (size_t)(bn + srow) * ldw + scol;

  f32x4 acc[FM][FN] = {};

  auto stage = [&](int buf, int k0) {
#pragma unroll
    for (int r = 0; r < RA; r++)
      __builtin_amdgcn_global_load_lds(GPTR(gA + (size_t)r * 32 * lda + k0),
                                       LPTR(&As[buf][(wv * 8 + r * 32) * BK]), 16, 0, 0);
#pragma unroll
    for (int r = 0; r < RB; r++)
      __builtin_amdgcn_global_load_lds(GPTR(gB + (size_t)r * 32 * ldw + k0),
                                       LPTR(&Bs[buf][(wv * 8 + r * 32) * BK]), 16, 0, 0);
  };

  auto compute = [&](int buf) {
#pragma unroll
    for (int kk = 0; kk < BK; kk += 32) {
      const int off = ((((kk >> 3) + lg) ^ r7) << 3);
      bf16x8 af[FM], bfr[FN];
#pragma unroll
      for (int m = 0; m < FM; m++)
        af[m] = *(const bf16x8*)&As[buf][(wr + m * 16 + la) * BK + off];
#pragma unroll
      for (int n = 0; n < FN; n++)
        bfr[n] = *(const bf16x8*)&Bs[buf][(wc + n * 16 + la) * BK + off];
#pragma unroll
      for (int m = 0; m < FM; m++)
#pragma unroll
        for (int n = 0; n < FN; n++)
          acc[m][n] = mfma16(af[m], bfr[n], acc[m][n]);
    }
  };

  if constexpr (PF) {
    // T3-minimum + T4: stage(next) BEFORE waiting tile t; never drain vmcnt to 0
    // in steady state. Wait covers loads issued one full compute-phase earlier.
    stage(0, kb);
    int buf = 0;
    const int NT = K / BK;
    for (int t = 0; t < NT; ++t) {
      if (t + 1 < NT) {
        stage(buf ^ 1, kb + (t + 1) * BK);
        if constexpr (RA + RB == 8)
          asm volatile("s_waitcnt vmcnt(8)" ::: "memory");
        else
          asm volatile("s_waitcnt vmcnt(6)" ::: "memory");
      } else {
        asm volatile("s_waitcnt vmcnt(0)" ::: "memory");
      }
      __builtin_amdgcn_s_barrier();          // tile t visible to all waves
      __builtin_amdgcn_sched_barrier(0);
      compute(buf);
      __builtin_amdgcn_s_barrier();          // all reads of buf done before restage
      buf ^= 1;
    }
  } else {
    for (int k0 = 0; k0 < K; k0 += BK) {
      __syncthreads();
      stage(0, kb + k0);
      __syncthreads();
      compute(0);
    }
  }

  const bool addb = (EPI != 3) || (blockIdx.z == 0);
  float bv[FN];
#pragma unroll
  for (int n = 0; n < FN; n++) bv[n] = addb ? bias[bn + wc + n * 16 + la] : 0.f;
#pragma unroll
  for (int m = 0; m < FM; m++) {
#pragma unroll
    for (int j = 0; j < 4; j++) {
      const int row = bm + wr + m * 16 + (lane >> 4) * 4 + j;
#pragma unroll
      for (int n = 0; n < FN; n++) {
        const int col = bn + wc + n * 16 + la;
        float v = acc[m][n][j] + bv[n];
        if constexpr (EPI == 1) v = fmaxf(v, 0.f);
        if constexpr (EPI == 2) {
          ((float*)outv)[(size_t)row * ldo + col] = v + C0[(size_t)row * ldc0 + col];
        } else if constexpr (EPI == 3) {
          if (blockIdx.z == 0)
            ((float*)outv)[(size_t)row * ldo + col] = v + C0[(size_t)row * ldc0 + col];
          else
            part[(size_t)row * ldo + col] = v;
        } else {
          ((u16*)outv)[(size_t)row * ldo + col] = f2bf(v);
        }
      }
    }
  }
}

// ---------------- fused attention (flash-style), hd=64, H=16 ----------------
template <bool CAUSAL>
__global__ __launch_bounds__(256) void attn_k(
    const u16* __restrict__ Qb, int ldq,
    const u16* __restrict__ Kb, int ldk,
    const u16* __restrict__ Vb, int ldv,
    const float* __restrict__ rel,   // [256,16]
    u16* __restrict__ Ob, int ldo,
    int Tq, int Tk) {
  __shared__ alignas(16) u16 Ks[128][72];
  __shared__ alignas(16) u16 Vt[64][136];
  __shared__ alignas(16) u16 Ps[4][16][136];
  __shared__ float biasl[256];
  const int tid = threadIdx.x, lane = tid & 63, w = tid >> 6;
  const int b = blockIdx.y >> 4, h = blockIdx.y & 15;
  const int q0 = blockIdx.x * 64;
  const int la = lane & 15, lg = lane >> 4;

  biasl[tid] = rel[tid * 16 + h];

  const int qr0 = q0 + w * 16;
  const u16* qp = Qb + (size_t)(b * Tq + qr0 + la) * ldq + h * 64 + lg * 8;
  const bf16x8 qf0 = *(const bf16x8*)qp;
  const bf16x8 qf1 = *(const bf16x8*)(qp + 32);

  float m[4], sm[4];
  f32x4 acc[4] = {};
#pragma unroll
  for (int j = 0; j < 4; j++) { m[j] = -1e30f; sm[j] = 0.f; }

  const int kv_end = CAUSAL ? (q0 + 64) : Tk;
  const int srow = tid >> 3, scol = (tid & 7) * 8;
  for (int kv0 = 0; kv0 < kv_end; kv0 += 128) {
    __syncthreads();
#pragma unroll
    for (int r = 0; r < 4; r++) {
      const int row = r * 32 + srow;
      const size_t gr = (size_t)(b * Tk + kv0 + row);
      *(u16x8*)&Ks[row][scol] = *(const u16x8*)&Kb[gr * ldk + h * 64 + scol];
      u16x8 vv = *(const u16x8*)&Vb[gr * ldv + h * 64 + scol];
#pragma unroll
      for (int j = 0; j < 8; j++) Vt[scol + j][row] = vv[j];
    }
    __syncthreads();

    f32x4 s[8];
#pragma unroll
    for (int kvt = 0; kvt < 8; kvt++) {
      const bf16x8 kf0 = *(const bf16x8*)&Ks[kvt * 16 + la][lg * 8];
      const bf16x8 kf1 = *(const bf16x8*)&Ks[kvt * 16 + la][32 + lg * 8];
      f32x4 t = {};
      t = mfma16(qf0, kf0, t);
      t = mfma16(qf1, kf1, t);
      const int kc = kv0 + kvt * 16 + la;
#pragma unroll
      for (int j = 0; j < 4; j++) {
        const int qr = qr0 + lg * 4 + j;
        const int rp = kc - qr;
        const int bucket = rp < 0 ? (rp > -127 ? -rp : 127) : (rp < 127 ? rp : 127) + 128;
        float sv = t[j] * 0.125f + biasl[bucket];
        if (CAUSAL && kc > qr) sv = -1e30f;
        s[kvt][j] = sv;
      }
    }
    float alpha[4];
#pragma unroll
    for (int j = 0; j < 4; j++) {
      float tm = s[0][j];
#pragma unroll
      for (int kvt = 1; kvt < 8; kvt++) tm = fmaxf(tm, s[kvt][j]);
#pragma unroll
      for (int off = 1; off < 16; off <<= 1) tm = fmaxf(tm, __shfl_xor(tm, off));
      const float mn = fmaxf(m[j], tm);
      alpha[j] = __expf(m[j] - mn);
      m[j] = mn;
      float r = 0.f;
#pragma unroll
      for (int kvt = 0; kvt < 8; kvt++) {
        const float p = __expf(s[kvt][j] - mn);
        s[kvt][j] = p;
        r += p;
      }
#pragma unroll
      for (int off = 1; off < 16; off <<= 1) r += __shfl_xor(r, off);
      sm[j] = sm[j] * alpha[j] + r;
    }
#pragma unroll
    for (int kvt = 0; kvt < 8; kvt++)
#pragma unroll
      for (int j = 0; j < 4; j++)
        Ps[w][lg * 4 + j][kvt * 16 + la] = f2bf(s[kvt][j]);
#pragma unroll
    for (int n = 0; n < 4; n++)
#pragma unroll
      for (int j = 0; j < 4; j++)
        acc[n][j] *= alpha[j];
#pragma unroll
    for (int kq = 0; kq < 4; kq++) {
      const bf16x8 pf = *(const bf16x8*)&Ps[w][la][kq * 32 + lg * 8];
#pragma unroll
      for (int n = 0; n < 4; n++) {
        const bf16x8 vf = *(const bf16x8*)&Vt[n * 16 + la][kq * 32 + lg * 8];
        acc[n] = mfma16(pf, vf, acc[n]);
      }
    }
  }
#pragma unroll
  for (int n = 0; n < 4; n++)
#pragma unroll
    for (int j = 0; j < 4; j++) {
      const int qr = qr0 + lg * 4 + j;
      Ob[(size_t)(b * Tq + qr) * ldo + h * 64 + n * 16 + la] = f2bf(acc[n][j] / sm[j]);
    }
}

extern "C" void kernel_launch(void* const* d_in, const int* in_sizes, int n_in,
                              void* d_out, int out_size, void* d_ws, size_t ws_size,
                              hipStream_t stream) {
  (void)in_sizes; (void)n_in; (void)out_size; (void)ws_size;
  const float* src       = (const float*)d_in[0];
  const float* tgt       = (const float*)d_in[1];
  const float* enc_in_w  = (const float*)d_in[2];
  const float* enc_in_b  = (const float*)d_in[3];
  const float* enc_out_w = (const float*)d_in[4];
  const float* enc_out_b = (const float*)d_in[5];
  const float* enc_ff1_w = (const float*)d_in[6];
  const float* enc_ff1_b = (const float*)d_in[7];
  const float* enc_ff2_w = (const float*)d_in[8];
  const float* enc_ff2_b = (const float*)d_in[9];
  const float* enc_n1_s  = (const float*)d_in[10];
  const float* enc_n1_b  = (const float*)d_in[11];
  const float* enc_n2_s  = (const float*)d_in[12];
  const float* enc_n2_b  = (const float*)d_in[13];
  const float* enc_rel   = (const float*)d_in[14];
  const float* dsa_in_w  = (const float*)d_in[15];
  const float* dsa_in_b  = (const float*)d_in[16];
  const float* dsa_out_w = (const float*)d_in[17];
  const float* dsa_out_b = (const float*)d_in[18];
  const float* dca_in_w  = (const float*)d_in[19];
  const float* dca_in_b  = (const float*)d_in[20];
  const float* dca_out_w = (const float*)d_in[21];
  const float* dca_out_b = (const float*)d_in[22];
  const float* dff1_w    = (const float*)d_in[23];
  const float* dff1_b    = (const float*)d_in[24];
  const float* dff2_w    = (const float*)d_in[25];
  const float* dff2_b    = (const float*)d_in[26];
  const float* dn1_s     = (const float*)d_in[27];
  const float* dn1_b     = (const float*)d_in[28];
  const float* dn2_s     = (const float*)d_in[29];
  const float* dn2_b     = (const float*)d_in[30];
  const float* dn3_s     = (const float*)d_in[31];
  const float* dn3_b     = (const float*)d_in[32];
  const float* drel_s    = (const float*)d_in[33];
  const float* drel_c    = (const float*)d_in[34];
  float* fo = (float*)d_out;

  // workspace layout (120 MiB total) — unchanged from round 4/5.
  // split-K partials: encoder ff2 -> d_out (scratch until dec-sa proj writes it);
  //                   decoder ff2 -> x_ws (dead after encoder).
  char* w8 = (char*)d_ws;
  float* x_ws  = (float*)(w8 + 0);          // 16 MiB  encoder residual / dec-ff2 partial
  u16* ln_buf  = (u16*)(w8 + 16777216);     //  8 MiB
  u16* qkv     = (u16*)(w8 + 25165824);     // 24 MiB
  u16* attn_o  = (u16*)(w8 + 50331648);     //  8 MiB
  u16* ffh     = qkv;                       // 32 MiB (aliases qkv+attn_o)
  u16* memb    = (u16*)(w8 + 58720256);     //  8 MiB  bf16 encoder memory
  u16* wb      = (u16*)(w8 + 67108864);     // 56 MiB  bf16 weights (contiguous)

  u16* w_enc_in  = wb;
  u16* w_enc_out = wb + 3145728;
  u16* w_enc_f1  = wb + 4194304;
  u16* w_enc_f2  = wb + 8388608;
  u16* w_dsa_in  = wb + 12582912;
  u16* w_dsa_out = wb + 15728640;
  u16* w_dca_in  = wb + 16777216;
  u16* w_dca_out = wb + 19922944;
  u16* w_dff1    = wb + 20971520;
  u16* w_dff2    = wb + 25165824;

  Srcs srcs = {{enc_in_w, enc_out_w, enc_ff1_w, enc_ff2_w, dsa_in_w,
                dsa_out_w, dca_in_w, dca_out_w, dff1_w, dff2_w}};
  cvt_all<<<dim3(28672), 256, 0, stream>>>(srcs, wb);

  // ---------------- encoder layer ----------------
  ln_k<<<dim3(4096), 256, 0, stream>>>(src, enc_n1_s, enc_n1_b, ln_buf);
  gemm_bt<128,2,0,0><<<dim3(24, 32), 256, 0, stream>>>(ln_buf, 1024, w_enc_in, 1024, enc_in_b, nullptr, 0, qkv, 3072, 1024, nullptr);
  attn_k<false><<<dim3(8, 128), 256, 0, stream>>>(qkv, 3072, qkv + 1024, 3072, qkv + 2048, 3072, enc_rel, attn_o, 1024, 512, 512);
  gemm_bt<64,4,2,1><<<dim3(16, 32), 256, 0, stream>>>(attn_o, 1024, w_enc_out, 1024, enc_out_b, src, 1024, x_ws, 1024, 1024, nullptr);
  ln_k<<<dim3(4096), 256, 0, stream>>>(x_ws, enc_n2_s, enc_n2_b, ln_buf);
  gemm_bt<128,2,1,0><<<dim3(32, 32), 256, 0, stream>>>(ln_buf, 1024, w_enc_f1, 1024, enc_ff1_b, nullptr, 0, ffh, 4096, 1024, nullptr);
  // ff2 split-K=2: z0 -> x_ws (= v+bias+C0), z1 -> fo (raw partial, d_out as scratch)
  gemm_bt<128,2,3,1><<<dim3(8, 32, 2), 256, 0, stream>>>(ffh, 4096, w_enc_f2, 4096, enc_ff2_b, x_ws, 1024, x_ws, 1024, 2048, fo);
  add_cvt<<<dim3(4096), 256, 0, stream>>>(x_ws, fo, memb);   // memb = bf16(x_ws + partial)

  // ---------------- decoder layer ----------------
  ln_k<<<dim3(4096), 256, 0, stream>>>(tgt, dn1_s, dn1_b, ln_buf);
  gemm_bt<128,2,0,0><<<dim3(24, 32), 256, 0, stream>>>(ln_buf, 1024, w_dsa_in, 1024, dsa_in_b, nullptr, 0, qkv, 3072, 1024, nullptr);
  attn_k<true><<<dim3(8, 128), 256, 0, stream>>>(qkv, 3072, qkv + 1024, 3072, qkv + 2048, 3072, drel_s, attn_o, 1024, 512, 512);
  gemm_bt<64,4,2,1><<<dim3(16, 32), 256, 0, stream>>>(attn_o, 1024, w_dsa_out, 1024, dsa_out_b, tgt, 1024, fo, 1024, 1024, nullptr);

  ln_k<<<dim3(4096), 256, 0, stream>>>(fo, dn2_s, dn2_b, ln_buf);
  gemm_bt<64,4,0,1><<<dim3(16, 32), 256, 0, stream>>>(ln_buf, 1024, w_dca_in, 1024, dca_in_b, nullptr, 0, qkv, 3072, 1024, nullptr);
  gemm_bt<128,2,0,0><<<dim3(16, 32), 256, 0, stream>>>(memb, 1024, w_dca_in + 1048576, 1024, dca_in_b + 1024, nullptr, 0, qkv + 1024, 3072, 1024, nullptr);
  attn_k<false><<<dim3(8, 128), 256, 0, stream>>>(qkv, 3072, qkv + 1024, 3072, qkv + 2048, 3072, drel_c, attn_o, 1024, 512, 512);
  gemm_bt<64,4,2,1><<<dim3(16, 32), 256, 0, stream>>>(attn_o, 1024, w_dca_out, 1024, dca_out_b, fo, 1024, fo, 1024, 1024, nullptr);

  ln_k<<<dim3(4096), 256, 0, stream>>>(fo, dn3_s, dn3_b, ln_buf);
  gemm_bt<128,2,1,0><<<dim3(32, 32), 256, 0, stream>>>(ln_buf, 1024, w_dff1, 1024, dff1_b, nullptr, 0, ffh, 4096, 1024, nullptr);
  // ff2 split-K=2: z0 -> fo (= v+bias+fo), z1 -> x_ws (raw partial)
  gemm_bt<128,2,3,1><<<dim3(8, 32, 2), 256, 0, stream>>>(ffh, 4096, w_dff2, 4096, dff2_b, fo, 1024, fo, 1024, 2048, x_ws);
  add_f32<<<dim3(4096), 256, 0, stream>>>(fo, x_ws);         // fo += partial
}